// Round 1
// baseline (2598.254 us; speedup 1.0000x reference)
//
#include <hip/hip_runtime.h>
#include <math.h>

#define N_ENT 40000
#define N_NODES 40500
#define EMB 256
#define N_EDGES 648000
#define BATCH 1024
#define BN_EPS 1e-5f

// ---------------------------------------------------------------- hamilton
__global__ void build_hamilton(const float* __restrict__ qw, float* __restrict__ H) {
    int idx = blockIdx.x * 256 + threadIdx.x;   // 65536 elements
    int i = idx >> 8, o = idx & 255;
    int p = i >> 6, i0 = i & 63;
    int q = o >> 6, o0 = o & 63;
    // H (4x4 blocks of 64x64), [p][q] -> component (r=0,i=1,j=2,k=3) and sign
    const int   ctab[16] = {0,1,2,3, 1,0,3,2, 2,3,0,1, 3,2,1,0};
    const float stab[16] = {1.f,1.f,1.f,1.f, -1.f,1.f,1.f,-1.f, -1.f,-1.f,1.f,1.f, -1.f,1.f,-1.f,1.f};
    int c = ctab[p*4+q];
    H[idx] = stab[p*4+q] * qw[i0*EMB + c*64 + o0];
}

// ---------------------------------------------------- support = emb @ H
// C[M,256] = A[M,256] * H[256,256], M = 40500 (row-guarded)
__global__ __launch_bounds__(256) void support_gemm(const float* __restrict__ A,
                                                    const float* __restrict__ H,
                                                    float* __restrict__ C) {
    __shared__ float As[64][17];
    __shared__ float Bs[16][68];
    const int bn = blockIdx.x, bm = blockIdx.y;
    const int row0 = bm * 64, col0 = bn * 64;
    const int t = threadIdx.x;
    const int tx = t & 15, ty = t >> 4;
    float acc[4][4] = {};
    for (int k0 = 0; k0 < 256; k0 += 16) {
        { // A tile 64x16
            int r = t >> 2, c = (t & 3) * 4;
            int gr = row0 + r;
            float4 v = make_float4(0.f, 0.f, 0.f, 0.f);
            if (gr < N_NODES) v = *(const float4*)(A + (size_t)gr * EMB + k0 + c);
            As[r][c+0] = v.x; As[r][c+1] = v.y; As[r][c+2] = v.z; As[r][c+3] = v.w;
        }
        { // B tile 16x64 (row-major direct)
            int r = t >> 4, c = (t & 15) * 4;
            float4 v = *(const float4*)(H + (size_t)(k0 + r) * EMB + col0 + c);
            Bs[r][c+0] = v.x; Bs[r][c+1] = v.y; Bs[r][c+2] = v.z; Bs[r][c+3] = v.w;
        }
        __syncthreads();
        #pragma unroll
        for (int k = 0; k < 16; ++k) {
            float a[4], b[4];
            #pragma unroll
            for (int i = 0; i < 4; ++i) a[i] = As[ty*4+i][k];
            #pragma unroll
            for (int j = 0; j < 4; ++j) b[j] = Bs[k][tx*4+j];
            #pragma unroll
            for (int i = 0; i < 4; ++i)
                #pragma unroll
                for (int j = 0; j < 4; ++j)
                    acc[i][j] = fmaf(a[i], b[j], acc[i][j]);
        }
        __syncthreads();
    }
    #pragma unroll
    for (int i = 0; i < 4; ++i) {
        int gr = row0 + ty*4 + i;
        if (gr < N_NODES) {
            #pragma unroll
            for (int j = 0; j < 4; ++j)
                C[(size_t)gr * EMB + col0 + tx*4 + j] = acc[i][j];
        }
    }
}

// ------------------------------------------------ scatter: agg[src] += v * support[dst]
__global__ __launch_bounds__(256) void scatter_agg(const float* __restrict__ support,
                                                   const int* __restrict__ src,
                                                   const int* __restrict__ dst,
                                                   const float* __restrict__ val,
                                                   float* __restrict__ agg) {
    int e = blockIdx.x * 4 + (threadIdx.x >> 6);
    if (e >= N_EDGES) return;
    int lane = threadIdx.x & 63;
    int s = src[e], d = dst[e];
    float v = val[e];
    float4 x = *(const float4*)(support + (size_t)d * EMB + lane * 4);
    float* a = agg + (size_t)s * EMB + lane * 4;
    atomicAdd(a + 0, v * x.x);
    atomicAdd(a + 1, v * x.y);
    atomicAdd(a + 2, v * x.z);
    atomicAdd(a + 3, v * x.w);
}

// ---------------------------------------------------------------- tanh (in place)
__global__ void tanh_k(float* __restrict__ x, int n4) {
    int i = blockIdx.x * blockDim.x + threadIdx.x;
    int stride = gridDim.x * blockDim.x;
    for (; i < n4; i += stride) {
        float4 v = ((const float4*)x)[i];
        v.x = tanhf(v.x); v.y = tanhf(v.y); v.z = tanhf(v.z); v.w = tanhf(v.w);
        ((float4*)x)[i] = v;
    }
}

// ---------------------------------------------------------------- hr = X[e1] * X[r+N_ENT]
__global__ void hr_k(const float* __restrict__ X, const int* __restrict__ e1,
                     const int* __restrict__ ri, float* __restrict__ hr) {
    int b = blockIdx.x, f = threadIdx.x;
    float h = X[(size_t)e1[b] * EMB + f];
    float r = X[((size_t)ri[b] + N_ENT) * EMB + f];
    hr[b * EMB + f] = h * r;
}

// ---------------------------------------------------------------- batchnorm stats
__global__ __launch_bounds__(256) void bn_stats(const float* __restrict__ hr,
                                                float* __restrict__ mean,
                                                float* __restrict__ var) {
    int f = blockIdx.x, t = threadIdx.x;
    float s = 0.f, sq = 0.f;
    for (int b = t; b < BATCH; b += 256) {
        float v = hr[b * EMB + f];
        s += v; sq += v * v;
    }
    #pragma unroll
    for (int off = 32; off > 0; off >>= 1) {
        s  += __shfl_down(s, off);
        sq += __shfl_down(sq, off);
    }
    __shared__ float ss[4], sqs[4];
    int w = t >> 6;
    if ((t & 63) == 0) { ss[w] = s; sqs[w] = sq; }
    __syncthreads();
    if (t == 0) {
        s  = ss[0] + ss[1] + ss[2] + ss[3];
        sq = sqs[0] + sqs[1] + sqs[2] + sqs[3];
        float m = s * (1.f / BATCH);
        mean[f] = m;
        var[f] = sq * (1.f / BATCH) - m * m;
    }
}

// ---------------------------------------------------------------- batchnorm apply
__global__ void bn_apply(float* __restrict__ hr, const float* __restrict__ mean,
                         const float* __restrict__ var, const float* __restrict__ gamma,
                         const float* __restrict__ beta) {
    int idx = blockIdx.x * 256 + threadIdx.x;   // 262144
    int f = idx & 255;
    float inv = rsqrtf(var[f] + BN_EPS);
    hr[idx] = (hr[idx] - mean[f]) * inv * gamma[f] + beta[f];
}

// ------------------------------------- out = sigmoid(hr @ X[:N_ENT]^T)  [1024 x 40000]
__global__ __launch_bounds__(256) void score_gemm(const float* __restrict__ hr,
                                                  const float* __restrict__ X,
                                                  float* __restrict__ out) {
    __shared__ float As[64][17];
    __shared__ float Bs[16][68];
    const int bn = blockIdx.x, bm = blockIdx.y;
    const int row0 = bm * 64, col0 = bn * 64;   // rows: batch, cols: entities
    const int t = threadIdx.x;
    const int tx = t & 15, ty = t >> 4;
    float acc[4][4] = {};
    for (int k0 = 0; k0 < 256; k0 += 16) {
        { // A tile 64x16 from hr (1024 rows, exact)
            int r = t >> 2, c = (t & 3) * 4;
            float4 v = *(const float4*)(hr + (size_t)(row0 + r) * EMB + k0 + c);
            As[r][c+0] = v.x; As[r][c+1] = v.y; As[r][c+2] = v.z; As[r][c+3] = v.w;
        }
        { // B tile: 64 entity rows x 16 k, transposed into Bs[k][n]
            int r = t >> 2, c = (t & 3) * 4;
            float4 v = *(const float4*)(X + (size_t)(col0 + r) * EMB + k0 + c);
            Bs[c+0][r] = v.x; Bs[c+1][r] = v.y; Bs[c+2][r] = v.z; Bs[c+3][r] = v.w;
        }
        __syncthreads();
        #pragma unroll
        for (int k = 0; k < 16; ++k) {
            float a[4], b[4];
            #pragma unroll
            for (int i = 0; i < 4; ++i) a[i] = As[ty*4+i][k];
            #pragma unroll
            for (int j = 0; j < 4; ++j) b[j] = Bs[k][tx*4+j];
            #pragma unroll
            for (int i = 0; i < 4; ++i)
                #pragma unroll
                for (int j = 0; j < 4; ++j)
                    acc[i][j] = fmaf(a[i], b[j], acc[i][j]);
        }
        __syncthreads();
    }
    #pragma unroll
    for (int i = 0; i < 4; ++i) {
        size_t row = row0 + ty*4 + i;
        #pragma unroll
        for (int j = 0; j < 4; ++j) {
            float s = 1.f / (1.f + expf(-acc[i][j]));
            out[row * (size_t)N_ENT + col0 + tx*4 + j] = s;
        }
    }
}

extern "C" void kernel_launch(void* const* d_in, const int* in_sizes, int n_in,
                              void* d_out, int out_size, void* d_ws, size_t ws_size,
                              hipStream_t stream) {
    const int*   e1    = (const int*)d_in[0];
    const int*   ri    = (const int*)d_in[1];
    // d_in[2] = lst_indexes (identity arange, unused)
    const float* emb   = (const float*)d_in[3];
    const float* qw    = (const float*)d_in[4];
    const int*   esrc  = (const int*)d_in[5];
    const int*   edst  = (const int*)d_in[6];
    const float* evalv = (const float*)d_in[7];
    const float* gamma = (const float*)d_in[8];
    const float* beta  = (const float*)d_in[9];
    float* out = (float*)d_out;

    const size_t NODE_F = (size_t)N_NODES * EMB;   // 10,368,000 floats
    float* support = (float*)d_ws;
    float* agg     = support + NODE_F;
    float* H       = agg + NODE_F;                 // 65536
    float* hr      = H + 65536;                    // 262144
    float* mean    = hr + 262144;                  // 256
    float* var     = mean + 256;                   // 256

    hipMemsetAsync(agg, 0, NODE_F * sizeof(float), stream);
    build_hamilton<<<256, 256, 0, stream>>>(qw, H);
    support_gemm<<<dim3(4, 633), 256, 0, stream>>>(emb, H, support);
    scatter_agg<<<N_EDGES / 4, 256, 0, stream>>>(support, esrc, edst, evalv, agg);
    tanh_k<<<2048, 256, 0, stream>>>(agg, (int)(NODE_F / 4));
    hr_k<<<BATCH, 256, 0, stream>>>(agg, e1, ri, hr);
    bn_stats<<<EMB, 256, 0, stream>>>(hr, mean, var);
    bn_apply<<<1024, 256, 0, stream>>>(hr, mean, var, gamma, beta);
    score_gemm<<<dim3(N_ENT / 64, BATCH / 64), 256, 0, stream>>>(hr, agg, out);
}

// Round 2
// 626.242 us; speedup vs baseline: 4.1490x; 4.1490x over previous
//
#include <hip/hip_runtime.h>
#include <math.h>

#define N_ENT 40000
#define N_NODES 40500
#define EMB 256
#define N_EDGES 648000
#define BATCH 1024
#define BN_EPS 1e-5f

// ---------------------------------------------------------------- hamilton
__global__ void build_hamilton(const float* __restrict__ qw, float* __restrict__ H) {
    int idx = blockIdx.x * 256 + threadIdx.x;   // 65536 elements
    int i = idx >> 8, o = idx & 255;
    int p = i >> 6, i0 = i & 63;
    int q = o >> 6, o0 = o & 63;
    const int   ctab[16] = {0,1,2,3, 1,0,3,2, 2,3,0,1, 3,2,1,0};
    const float stab[16] = {1.f,1.f,1.f,1.f, -1.f,1.f,1.f,-1.f, -1.f,-1.f,1.f,1.f, -1.f,1.f,-1.f,1.f};
    int c = ctab[p*4+q];
    H[idx] = stab[p*4+q] * qw[i0*EMB + c*64 + o0];
}

// ---------------------------------------------------- support = emb @ H
__global__ __launch_bounds__(256) void support_gemm(const float* __restrict__ A,
                                                    const float* __restrict__ H,
                                                    float* __restrict__ C) {
    __shared__ float As[64][17];
    __shared__ float Bs[16][68];
    const int bn = blockIdx.x, bm = blockIdx.y;
    const int row0 = bm * 64, col0 = bn * 64;
    const int t = threadIdx.x;
    const int tx = t & 15, ty = t >> 4;
    float acc[4][4] = {};
    for (int k0 = 0; k0 < 256; k0 += 16) {
        {
            int r = t >> 2, c = (t & 3) * 4;
            int gr = row0 + r;
            float4 v = make_float4(0.f, 0.f, 0.f, 0.f);
            if (gr < N_NODES) v = *(const float4*)(A + (size_t)gr * EMB + k0 + c);
            As[r][c+0] = v.x; As[r][c+1] = v.y; As[r][c+2] = v.z; As[r][c+3] = v.w;
        }
        {
            int r = t >> 4, c = (t & 15) * 4;
            float4 v = *(const float4*)(H + (size_t)(k0 + r) * EMB + col0 + c);
            Bs[r][c+0] = v.x; Bs[r][c+1] = v.y; Bs[r][c+2] = v.z; Bs[r][c+3] = v.w;
        }
        __syncthreads();
        #pragma unroll
        for (int k = 0; k < 16; ++k) {
            float a[4], b[4];
            #pragma unroll
            for (int i = 0; i < 4; ++i) a[i] = As[ty*4+i][k];
            #pragma unroll
            for (int j = 0; j < 4; ++j) b[j] = Bs[k][tx*4+j];
            #pragma unroll
            for (int i = 0; i < 4; ++i)
                #pragma unroll
                for (int j = 0; j < 4; ++j)
                    acc[i][j] = fmaf(a[i], b[j], acc[i][j]);
        }
        __syncthreads();
    }
    #pragma unroll
    for (int i = 0; i < 4; ++i) {
        int gr = row0 + ty*4 + i;
        if (gr < N_NODES) {
            #pragma unroll
            for (int j = 0; j < 4; ++j)
                C[(size_t)gr * EMB + col0 + tx*4 + j] = acc[i][j];
        }
    }
}

// ---------------------------------------------------------------- CSR build
__global__ void hist_k(const int* __restrict__ src, int* __restrict__ cnt) {
    int e = blockIdx.x * 256 + threadIdx.x;
    if (e < N_EDGES) atomicAdd(&cnt[src[e]], 1);
}

__global__ __launch_bounds__(1024) void scan_k(const int* __restrict__ cnt,
                                               int* __restrict__ row_start) {
    __shared__ int wsum[16];
    __shared__ int carry_s;
    const int t = threadIdx.x;
    const int lane = t & 63, wid = t >> 6;
    if (t == 0) carry_s = 0;
    __syncthreads();
    for (int base = 0; base < N_NODES; base += 1024) {
        int idx = base + t;
        int v = (idx < N_NODES) ? cnt[idx] : 0;
        // wave inclusive scan
        int incl = v;
        #pragma unroll
        for (int off = 1; off < 64; off <<= 1) {
            int u = __shfl_up(incl, off);
            if (lane >= off) incl += u;
        }
        if (lane == 63) wsum[wid] = incl;
        __syncthreads();
        if (t < 16) {
            int wv = wsum[t];
            #pragma unroll
            for (int off = 1; off < 16; off <<= 1) {
                int u = __shfl_up(wv, off);
                if (t >= off) wv += u;
            }
            wsum[t] = wv;   // inclusive wave-sum scan
        }
        __syncthreads();
        int woff = (wid > 0) ? wsum[wid - 1] : 0;
        incl += woff;
        int c = carry_s;
        if (idx < N_NODES) row_start[idx] = c + incl - v;
        __syncthreads();
        if (t == 1023) carry_s = c + incl;
        __syncthreads();
    }
    if (t == 0) row_start[N_NODES] = carry_s;
}

__global__ void place_edges(const int* __restrict__ src, const int* __restrict__ dst,
                            const float* __restrict__ val, int* __restrict__ cursor,
                            int* __restrict__ dst_s, float* __restrict__ val_s) {
    int e = blockIdx.x * 256 + threadIdx.x;
    if (e >= N_EDGES) return;
    int pos = atomicAdd(&cursor[src[e]], 1);
    dst_s[pos] = dst[e];
    val_s[pos] = val[e];
}

// ------------------------------------- X[row] = tanh( sum_e val * support[dst] )
__global__ __launch_bounds__(256) void spmm_tanh(const int* __restrict__ row_start,
                                                 const int* __restrict__ dst_s,
                                                 const float* __restrict__ val_s,
                                                 const float* __restrict__ support,
                                                 float* __restrict__ X) {
    int row = blockIdx.x * 4 + (threadIdx.x >> 6);
    if (row >= N_NODES) return;
    int lane = threadIdx.x & 63;
    int beg = row_start[row], end = row_start[row + 1];
    float4 acc = make_float4(0.f, 0.f, 0.f, 0.f);
    for (int i = beg; i < end; ++i) {
        int d = dst_s[i];
        float v = val_s[i];
        float4 x = *(const float4*)(support + (size_t)d * EMB + lane * 4);
        acc.x = fmaf(v, x.x, acc.x);
        acc.y = fmaf(v, x.y, acc.y);
        acc.z = fmaf(v, x.z, acc.z);
        acc.w = fmaf(v, x.w, acc.w);
    }
    float4 o;
    o.x = tanhf(acc.x); o.y = tanhf(acc.y); o.z = tanhf(acc.z); o.w = tanhf(acc.w);
    *(float4*)(X + (size_t)row * EMB + lane * 4) = o;
}

// ---------------------------------------------------------------- hr = X[e1] * X[r+N_ENT]
__global__ void hr_k(const float* __restrict__ X, const int* __restrict__ e1,
                     const int* __restrict__ ri, float* __restrict__ hr) {
    int b = blockIdx.x, f = threadIdx.x;
    float h = X[(size_t)e1[b] * EMB + f];
    float r = X[((size_t)ri[b] + N_ENT) * EMB + f];
    hr[b * EMB + f] = h * r;
}

// ---------------------------------------------------------------- batchnorm stats
__global__ __launch_bounds__(256) void bn_stats(const float* __restrict__ hr,
                                                float* __restrict__ mean,
                                                float* __restrict__ var) {
    int f = blockIdx.x, t = threadIdx.x;
    float s = 0.f, sq = 0.f;
    for (int b = t; b < BATCH; b += 256) {
        float v = hr[b * EMB + f];
        s += v; sq += v * v;
    }
    #pragma unroll
    for (int off = 32; off > 0; off >>= 1) {
        s  += __shfl_down(s, off);
        sq += __shfl_down(sq, off);
    }
    __shared__ float ss[4], sqs[4];
    int w = t >> 6;
    if ((t & 63) == 0) { ss[w] = s; sqs[w] = sq; }
    __syncthreads();
    if (t == 0) {
        s  = ss[0] + ss[1] + ss[2] + ss[3];
        sq = sqs[0] + sqs[1] + sqs[2] + sqs[3];
        float m = s * (1.f / BATCH);
        mean[f] = m;
        var[f] = sq * (1.f / BATCH) - m * m;
    }
}

// ---------------------------------------------------------------- batchnorm apply
__global__ void bn_apply(float* __restrict__ hr, const float* __restrict__ mean,
                         const float* __restrict__ var, const float* __restrict__ gamma,
                         const float* __restrict__ beta) {
    int idx = blockIdx.x * 256 + threadIdx.x;   // 262144
    int f = idx & 255;
    float inv = rsqrtf(var[f] + BN_EPS);
    hr[idx] = (hr[idx] - mean[f]) * inv * gamma[f] + beta[f];
}

// ------------------------------------- out = sigmoid(hr @ X[:N_ENT]^T)  [1024 x 40000]
__global__ __launch_bounds__(256) void score_gemm(const float* __restrict__ hr,
                                                  const float* __restrict__ X,
                                                  float* __restrict__ out) {
    __shared__ float As[64][17];
    __shared__ float Bs[16][68];
    const int bn = blockIdx.x, bm = blockIdx.y;
    const int row0 = bm * 64, col0 = bn * 64;
    const int t = threadIdx.x;
    const int tx = t & 15, ty = t >> 4;
    float acc[4][4] = {};
    for (int k0 = 0; k0 < 256; k0 += 16) {
        {
            int r = t >> 2, c = (t & 3) * 4;
            float4 v = *(const float4*)(hr + (size_t)(row0 + r) * EMB + k0 + c);
            As[r][c+0] = v.x; As[r][c+1] = v.y; As[r][c+2] = v.z; As[r][c+3] = v.w;
        }
        {
            int r = t >> 2, c = (t & 3) * 4;
            float4 v = *(const float4*)(X + (size_t)(col0 + r) * EMB + k0 + c);
            Bs[c+0][r] = v.x; Bs[c+1][r] = v.y; Bs[c+2][r] = v.z; Bs[c+3][r] = v.w;
        }
        __syncthreads();
        #pragma unroll
        for (int k = 0; k < 16; ++k) {
            float a[4], b[4];
            #pragma unroll
            for (int i = 0; i < 4; ++i) a[i] = As[ty*4+i][k];
            #pragma unroll
            for (int j = 0; j < 4; ++j) b[j] = Bs[k][tx*4+j];
            #pragma unroll
            for (int i = 0; i < 4; ++i)
                #pragma unroll
                for (int j = 0; j < 4; ++j)
                    acc[i][j] = fmaf(a[i], b[j], acc[i][j]);
        }
        __syncthreads();
    }
    #pragma unroll
    for (int i = 0; i < 4; ++i) {
        size_t row = row0 + ty*4 + i;
        #pragma unroll
        for (int j = 0; j < 4; ++j) {
            float s = 1.f / (1.f + expf(-acc[i][j]));
            out[row * (size_t)N_ENT + col0 + tx*4 + j] = s;
        }
    }
}

extern "C" void kernel_launch(void* const* d_in, const int* in_sizes, int n_in,
                              void* d_out, int out_size, void* d_ws, size_t ws_size,
                              hipStream_t stream) {
    const int*   e1    = (const int*)d_in[0];
    const int*   ri    = (const int*)d_in[1];
    const float* emb   = (const float*)d_in[3];
    const float* qw    = (const float*)d_in[4];
    const int*   esrc  = (const int*)d_in[5];
    const int*   edst  = (const int*)d_in[6];
    const float* evalv = (const float*)d_in[7];
    const float* gamma = (const float*)d_in[8];
    const float* beta  = (const float*)d_in[9];
    float* out = (float*)d_out;

    const size_t NODE_F = (size_t)N_NODES * EMB;   // 10,368,000 floats
    float* support   = (float*)d_ws;
    float* X         = support + NODE_F;
    float* H         = X + NODE_F;                 // 65536
    float* hr        = H + 65536;                  // 262144
    float* mean      = hr + 262144;                // 256
    float* var       = mean + 256;                 // 256
    int*   row_start = (int*)(var + 256);          // N_NODES+1
    int*   cnt       = row_start + (N_NODES + 1);  // N_NODES (also reused as cursor)
    int*   dst_s     = cnt + N_NODES;              // N_EDGES
    float* val_s     = (float*)(dst_s + N_EDGES);  // N_EDGES

    // CSR build (no fp atomics anywhere)
    hipMemsetAsync(cnt, 0, N_NODES * sizeof(int), stream);
    hist_k<<<(N_EDGES + 255) / 256, 256, 0, stream>>>(esrc, cnt);
    scan_k<<<1, 1024, 0, stream>>>(cnt, row_start);
    hipMemcpyAsync(cnt, row_start, N_NODES * sizeof(int), hipMemcpyDeviceToDevice, stream);

    build_hamilton<<<256, 256, 0, stream>>>(qw, H);
    support_gemm<<<dim3(4, 633), 256, 0, stream>>>(emb, H, support);

    place_edges<<<(N_EDGES + 255) / 256, 256, 0, stream>>>(esrc, edst, evalv, cnt, dst_s, val_s);
    spmm_tanh<<<N_NODES / 4, 256, 0, stream>>>(row_start, dst_s, val_s, support, X);

    hr_k<<<BATCH, 256, 0, stream>>>(X, e1, ri, hr);
    bn_stats<<<EMB, 256, 0, stream>>>(hr, mean, var);
    bn_apply<<<1024, 256, 0, stream>>>(hr, mean, var, gamma, beta);
    score_gemm<<<dim3(N_ENT / 64, BATCH / 64), 256, 0, stream>>>(hr, X, out);
}

// Round 3
// 458.317 us; speedup vs baseline: 5.6691x; 1.3664x over previous
//
#include <hip/hip_runtime.h>
#include <math.h>

#define N_ENT 40000
#define N_NODES 40500
#define EMB 256
#define N_EDGES 648000
#define BATCH 1024
#define BN_EPS 1e-5f

typedef __attribute__((ext_vector_type(8))) short short8;
typedef __attribute__((ext_vector_type(4))) float f32x4;

__device__ inline short f2bf(float f) {
    unsigned u = __float_as_uint(f);
    return (short)((u + 0x7FFFu + ((u >> 16) & 1u)) >> 16);
}
__device__ inline float bf2f(short s) {
    return __uint_as_float(((unsigned)(unsigned short)s) << 16);
}

// ---------------------------------------------------------------- hamilton
__global__ void build_hamilton(const float* __restrict__ qw, float* __restrict__ H) {
    int idx = blockIdx.x * 256 + threadIdx.x;   // 65536 elements
    int i = idx >> 8, o = idx & 255;
    int p = i >> 6, i0 = i & 63;
    int q = o >> 6, o0 = o & 63;
    const int   ctab[16] = {0,1,2,3, 1,0,3,2, 2,3,0,1, 3,2,1,0};
    const float stab[16] = {1.f,1.f,1.f,1.f, -1.f,1.f,1.f,-1.f, -1.f,-1.f,1.f,1.f, -1.f,1.f,-1.f,1.f};
    int c = ctab[p*4+q];
    H[idx] = stab[p*4+q] * qw[i0*EMB + c*64 + o0];
}

// ---------------------------------------------------- support = emb @ H (fp32)
__global__ __launch_bounds__(256) void support_gemm(const float* __restrict__ A,
                                                    const float* __restrict__ H,
                                                    float* __restrict__ C) {
    __shared__ float As[64][17];
    __shared__ float Bs[16][68];
    const int bn = blockIdx.x, bm = blockIdx.y;
    const int row0 = bm * 64, col0 = bn * 64;
    const int t = threadIdx.x;
    const int tx = t & 15, ty = t >> 4;
    float acc[4][4] = {};
    for (int k0 = 0; k0 < 256; k0 += 16) {
        {
            int r = t >> 2, c = (t & 3) * 4;
            int gr = row0 + r;
            float4 v = make_float4(0.f, 0.f, 0.f, 0.f);
            if (gr < N_NODES) v = *(const float4*)(A + (size_t)gr * EMB + k0 + c);
            As[r][c+0] = v.x; As[r][c+1] = v.y; As[r][c+2] = v.z; As[r][c+3] = v.w;
        }
        {
            int r = t >> 4, c = (t & 15) * 4;
            float4 v = *(const float4*)(H + (size_t)(k0 + r) * EMB + col0 + c);
            Bs[r][c+0] = v.x; Bs[r][c+1] = v.y; Bs[r][c+2] = v.z; Bs[r][c+3] = v.w;
        }
        __syncthreads();
        #pragma unroll
        for (int k = 0; k < 16; ++k) {
            float a[4], b[4];
            #pragma unroll
            for (int i = 0; i < 4; ++i) a[i] = As[ty*4+i][k];
            #pragma unroll
            for (int j = 0; j < 4; ++j) b[j] = Bs[k][tx*4+j];
            #pragma unroll
            for (int i = 0; i < 4; ++i)
                #pragma unroll
                for (int j = 0; j < 4; ++j)
                    acc[i][j] = fmaf(a[i], b[j], acc[i][j]);
        }
        __syncthreads();
    }
    #pragma unroll
    for (int i = 0; i < 4; ++i) {
        int gr = row0 + ty*4 + i;
        if (gr < N_NODES) {
            #pragma unroll
            for (int j = 0; j < 4; ++j)
                C[(size_t)gr * EMB + col0 + tx*4 + j] = acc[i][j];
        }
    }
}

// ---------------------------------------------------------------- CSR build
__global__ void hist_k(const int* __restrict__ src, int* __restrict__ cnt) {
    int e = blockIdx.x * 256 + threadIdx.x;
    if (e < N_EDGES) atomicAdd(&cnt[src[e]], 1);
}

__global__ __launch_bounds__(1024) void scan_k(const int* __restrict__ cnt,
                                               int* __restrict__ row_start) {
    __shared__ int wsum[16];
    __shared__ int carry_s;
    const int t = threadIdx.x;
    const int lane = t & 63, wid = t >> 6;
    if (t == 0) carry_s = 0;
    __syncthreads();
    for (int base = 0; base < N_NODES; base += 1024) {
        int idx = base + t;
        int v = (idx < N_NODES) ? cnt[idx] : 0;
        int incl = v;
        #pragma unroll
        for (int off = 1; off < 64; off <<= 1) {
            int u = __shfl_up(incl, off);
            if (lane >= off) incl += u;
        }
        if (lane == 63) wsum[wid] = incl;
        __syncthreads();
        if (t < 16) {
            int wv = wsum[t];
            #pragma unroll
            for (int off = 1; off < 16; off <<= 1) {
                int u = __shfl_up(wv, off);
                if (t >= off) wv += u;
            }
            wsum[t] = wv;
        }
        __syncthreads();
        int woff = (wid > 0) ? wsum[wid - 1] : 0;
        incl += woff;
        int c = carry_s;
        if (idx < N_NODES) row_start[idx] = c + incl - v;
        __syncthreads();
        if (t == 1023) carry_s = c + incl;
        __syncthreads();
    }
    if (t == 0) row_start[N_NODES] = carry_s;
}

__global__ void place_edges(const int* __restrict__ src, const int* __restrict__ dst,
                            const float* __restrict__ val, int* __restrict__ cursor,
                            int* __restrict__ dst_s, float* __restrict__ val_s) {
    int e = blockIdx.x * 256 + threadIdx.x;
    if (e >= N_EDGES) return;
    int pos = atomicAdd(&cursor[src[e]], 1);
    dst_s[pos] = dst[e];
    val_s[pos] = val[e];
}

// ------------------------------------- X[row] = tanh( sum_e val * support[dst] )
__global__ __launch_bounds__(256) void spmm_tanh(const int* __restrict__ row_start,
                                                 const int* __restrict__ dst_s,
                                                 const float* __restrict__ val_s,
                                                 const float* __restrict__ support,
                                                 float* __restrict__ X) {
    int row = blockIdx.x * 4 + (threadIdx.x >> 6);
    if (row >= N_NODES) return;
    int lane = threadIdx.x & 63;
    int beg = row_start[row], end = row_start[row + 1];
    float4 acc = make_float4(0.f, 0.f, 0.f, 0.f);
    for (int i = beg; i < end; ++i) {
        int d = dst_s[i];
        float v = val_s[i];
        float4 x = *(const float4*)(support + (size_t)d * EMB + lane * 4);
        acc.x = fmaf(v, x.x, acc.x);
        acc.y = fmaf(v, x.y, acc.y);
        acc.z = fmaf(v, x.z, acc.z);
        acc.w = fmaf(v, x.w, acc.w);
    }
    float4 o;
    o.x = tanhf(acc.x); o.y = tanhf(acc.y); o.z = tanhf(acc.z); o.w = tanhf(acc.w);
    *(float4*)(X + (size_t)row * EMB + lane * 4) = o;
}

// ---------------------------------------------------------------- X fp32 -> bf16
__global__ void cvt_X(const float* __restrict__ X, short* __restrict__ Xb) {
    int i = (blockIdx.x * 256 + threadIdx.x) * 4;   // NODE_F elements total
    float4 v = *(const float4*)(X + i);
    short4 o;
    o.x = f2bf(v.x); o.y = f2bf(v.y); o.z = f2bf(v.z); o.w = f2bf(v.w);
    *(short4*)(Xb + i) = o;
}

// ---------------------------------------------------------------- hr = X[e1] * X[r+N_ENT]
__global__ void hr_k(const float* __restrict__ X, const int* __restrict__ e1,
                     const int* __restrict__ ri, float* __restrict__ hr) {
    int b = blockIdx.x, f = threadIdx.x;
    float h = X[(size_t)e1[b] * EMB + f];
    float r = X[((size_t)ri[b] + N_ENT) * EMB + f];
    hr[b * EMB + f] = h * r;
}

// ---------------------------------------------------------------- batchnorm stats
__global__ __launch_bounds__(256) void bn_stats(const float* __restrict__ hr,
                                                float* __restrict__ mean,
                                                float* __restrict__ var) {
    int f = blockIdx.x, t = threadIdx.x;
    float s = 0.f, sq = 0.f;
    for (int b = t; b < BATCH; b += 256) {
        float v = hr[b * EMB + f];
        s += v; sq += v * v;
    }
    #pragma unroll
    for (int off = 32; off > 0; off >>= 1) {
        s  += __shfl_down(s, off);
        sq += __shfl_down(sq, off);
    }
    __shared__ float ss[4], sqs[4];
    int w = t >> 6;
    if ((t & 63) == 0) { ss[w] = s; sqs[w] = sq; }
    __syncthreads();
    if (t == 0) {
        s  = ss[0] + ss[1] + ss[2] + ss[3];
        sq = sqs[0] + sqs[1] + sqs[2] + sqs[3];
        float m = s * (1.f / BATCH);
        mean[f] = m;
        var[f] = sq * (1.f / BATCH) - m * m;
    }
}

// --------------------------------------------- batchnorm apply + hi/lo bf16 split
__global__ void bn_apply_split(const float* __restrict__ hr, const float* __restrict__ mean,
                               const float* __restrict__ var, const float* __restrict__ gamma,
                               const float* __restrict__ beta,
                               short* __restrict__ hi, short* __restrict__ lo) {
    int idx = blockIdx.x * 256 + threadIdx.x;   // 262144
    int f = idx & 255;
    float inv = rsqrtf(var[f] + BN_EPS);
    float v = (hr[idx] - mean[f]) * inv * gamma[f] + beta[f];
    short h = f2bf(v);
    hi[idx] = h;
    lo[idx] = f2bf(v - bf2f(h));
}

// ------------- out = sigmoid((hr_hi+hr_lo) @ Xb[:N_ENT]^T)  [1024 x 40000], MFMA
__global__ __launch_bounds__(256) void score_gemm_mfma(const short* __restrict__ hrhi,
                                                       const short* __restrict__ hrlo,
                                                       const short* __restrict__ Xb,
                                                       float* __restrict__ out) {
    // block tile 64(M) x 160(N); 4 waves in 2x2; wave tile 32x80 = 2x5 16x16 frags
    const int wid  = threadIdx.x >> 6;
    const int lane = threadIdx.x & 63;
    const int wr = wid >> 1, wc = wid & 1;
    const int row0 = blockIdx.y * 64 + wr * 32;
    const int col0 = blockIdx.x * 160 + wc * 80;
    const int fr = lane & 15;       // A-row / B-col within fragment
    const int kg = lane >> 4;       // k-group (0..3), 8 consecutive k each
    f32x4 acc[2][5] = {};
    #pragma unroll 2
    for (int kb = 0; kb < 8; ++kb) {
        const int koff = kb * 32 + kg * 8;
        short8 a_hi[2], a_lo[2], b[5];
        #pragma unroll
        for (int i = 0; i < 2; ++i) {
            size_t off = (size_t)(row0 + i * 16 + fr) * EMB + koff;
            a_hi[i] = *(const short8*)(hrhi + off);
            a_lo[i] = *(const short8*)(hrlo + off);
        }
        #pragma unroll
        for (int j = 0; j < 5; ++j)
            b[j] = *(const short8*)(Xb + (size_t)(col0 + j * 16 + fr) * EMB + koff);
        #pragma unroll
        for (int i = 0; i < 2; ++i)
            #pragma unroll
            for (int j = 0; j < 5; ++j) {
                acc[i][j] = __builtin_amdgcn_mfma_f32_16x16x32_bf16(a_hi[i], b[j], acc[i][j], 0, 0, 0);
                acc[i][j] = __builtin_amdgcn_mfma_f32_16x16x32_bf16(a_lo[i], b[j], acc[i][j], 0, 0, 0);
            }
    }
    // C/D mapping (m89-verified): col = lane&15, row = (lane>>4)*4 + reg
    #pragma unroll
    for (int i = 0; i < 2; ++i) {
        int rbase = row0 + i * 16 + (lane >> 4) * 4;
        #pragma unroll
        for (int j = 0; j < 5; ++j) {
            int c = col0 + j * 16 + (lane & 15);
            #pragma unroll
            for (int r = 0; r < 4; ++r) {
                float s = 1.f / (1.f + __expf(-acc[i][j][r]));
                out[(size_t)(rbase + r) * N_ENT + c] = s;
            }
        }
    }
}

extern "C" void kernel_launch(void* const* d_in, const int* in_sizes, int n_in,
                              void* d_out, int out_size, void* d_ws, size_t ws_size,
                              hipStream_t stream) {
    const int*   e1    = (const int*)d_in[0];
    const int*   ri    = (const int*)d_in[1];
    const float* emb   = (const float*)d_in[3];
    const float* qw    = (const float*)d_in[4];
    const int*   esrc  = (const int*)d_in[5];
    const int*   edst  = (const int*)d_in[6];
    const float* evalv = (const float*)d_in[7];
    const float* gamma = (const float*)d_in[8];
    const float* beta  = (const float*)d_in[9];
    float* out = (float*)d_out;

    const size_t NODE_F = (size_t)N_NODES * EMB;   // 10,368,000 floats
    float* support   = (float*)d_ws;
    float* X         = support + NODE_F;
    float* H         = X + NODE_F;                 // 65536
    float* hr        = H + 65536;                  // 262144
    float* mean      = hr + 262144;                // 256
    float* var       = mean + 256;                 // 256
    int*   row_start = (int*)(var + 256);          // N_NODES+1
    int*   cnt       = row_start + (N_NODES + 1);  // N_NODES (cursor)
    int*   dst_s     = cnt + N_NODES;              // N_EDGES
    float* val_s     = (float*)(dst_s + N_EDGES);  // N_EDGES
    short* hrhi      = (short*)(val_s + N_EDGES);  // 262144 shorts
    short* hrlo      = hrhi + 262144;              // 262144 shorts
    short* Xb        = (short*)support;            // alias: support dead after spmm_tanh

    // CSR build (no fp atomics anywhere)
    hipMemsetAsync(cnt, 0, N_NODES * sizeof(int), stream);
    hist_k<<<(N_EDGES + 255) / 256, 256, 0, stream>>>(esrc, cnt);
    scan_k<<<1, 1024, 0, stream>>>(cnt, row_start);
    hipMemcpyAsync(cnt, row_start, N_NODES * sizeof(int), hipMemcpyDeviceToDevice, stream);

    build_hamilton<<<256, 256, 0, stream>>>(qw, H);
    support_gemm<<<dim3(4, 633), 256, 0, stream>>>(emb, H, support);

    place_edges<<<(N_EDGES + 255) / 256, 256, 0, stream>>>(esrc, edst, evalv, cnt, dst_s, val_s);
    spmm_tanh<<<N_NODES / 4, 256, 0, stream>>>(row_start, dst_s, val_s, support, X);
    cvt_X<<<(int)(NODE_F / 1024), 256, 0, stream>>>(X, Xb);

    hr_k<<<BATCH, 256, 0, stream>>>(X, e1, ri, hr);
    bn_stats<<<EMB, 256, 0, stream>>>(hr, mean, var);
    bn_apply_split<<<1024, 256, 0, stream>>>(hr, mean, var, gamma, beta, hrhi, hrlo);
    score_gemm_mfma<<<dim3(N_ENT / 160, BATCH / 64), 256, 0, stream>>>(hrhi, hrlo, Xb, out);
}

// Round 4
// 452.774 us; speedup vs baseline: 5.7385x; 1.0122x over previous
//
#include <hip/hip_runtime.h>
#include <math.h>

#define N_ENT 40000
#define N_NODES 40500
#define EMB 256
#define N_EDGES 648000
#define BATCH 1024
#define BN_EPS 1e-5f

typedef __attribute__((ext_vector_type(8))) short short8;
typedef __attribute__((ext_vector_type(4))) float f32x4;

__device__ inline short f2bf(float f) {
    unsigned u = __float_as_uint(f);
    return (short)((u + 0x7FFFu + ((u >> 16) & 1u)) >> 16);
}
__device__ inline float bf2f(short s) {
    return __uint_as_float(((unsigned)(unsigned short)s) << 16);
}

// ------------------------------------------- hamilton, transposed, bf16 hi/lo
// Ht[o][i] = H[i][o];  H[i][o] = sign(p,q) * qw[i0][c*64+o0]
__global__ void build_hamilton_t(const float* __restrict__ qw,
                                 short* __restrict__ Hthi, short* __restrict__ Htlo) {
    int idx = blockIdx.x * 256 + threadIdx.x;   // 65536; idx = o*256 + i
    int o = idx >> 8, i = idx & 255;
    int p = i >> 6, i0 = i & 63;
    int q = o >> 6, o0 = o & 63;
    const int   ctab[16] = {0,1,2,3, 1,0,3,2, 2,3,0,1, 3,2,1,0};
    const float stab[16] = {1.f,1.f,1.f,1.f, -1.f,1.f,1.f,-1.f, -1.f,-1.f,1.f,1.f, -1.f,1.f,-1.f,1.f};
    float v = stab[p*4+q] * qw[i0*EMB + ctab[p*4+q]*64 + o0];
    short h = f2bf(v);
    Hthi[idx] = h;
    Htlo[idx] = f2bf(v - bf2f(h));
}

// ---------------------------------------------------------------- emb -> bf16 hi/lo
__global__ void cvt_emb(const float* __restrict__ e, short* __restrict__ hi,
                        short* __restrict__ lo) {
    size_t i = (size_t)(blockIdx.x * 256 + threadIdx.x) * 4;   // NODE_F elements
    float4 v = *(const float4*)(e + i);
    short4 h, l;
    h.x = f2bf(v.x); l.x = f2bf(v.x - bf2f(h.x));
    h.y = f2bf(v.y); l.y = f2bf(v.y - bf2f(h.y));
    h.z = f2bf(v.z); l.z = f2bf(v.z - bf2f(h.z));
    h.w = f2bf(v.w); l.w = f2bf(v.w - bf2f(h.w));
    *(short4*)(hi + i) = h;
    *(short4*)(lo + i) = l;
}

// ---------------------- support = emb @ H via 3-term hi/lo MFMA (~fp32 exact)
// block: 64 rows x 256 cols (full N), 4 waves 2x2, wave 32x128 (2x8 frags)
__global__ __launch_bounds__(256) void support_mfma(const short* __restrict__ ehi,
                                                    const short* __restrict__ elo,
                                                    const short* __restrict__ Hthi,
                                                    const short* __restrict__ Htlo,
                                                    float* __restrict__ C) {
    const int wid  = threadIdx.x >> 6;
    const int lane = threadIdx.x & 63;
    const int wr = wid >> 1, wc = wid & 1;
    const int row0 = blockIdx.x * 64 + wr * 32;
    const int col0 = wc * 128;
    const int fr = lane & 15;
    const int kg = lane >> 4;
    f32x4 acc[2][8] = {};
    for (int kb = 0; kb < 8; ++kb) {
        const int koff = kb * 32 + kg * 8;
        short8 ah[2], al[2];
        #pragma unroll
        for (int i = 0; i < 2; ++i) {
            int r = row0 + i * 16 + fr;
            if (r > N_NODES - 1) r = N_NODES - 1;
            size_t off = (size_t)r * EMB + koff;
            ah[i] = *(const short8*)(ehi + off);
            al[i] = *(const short8*)(elo + off);
        }
        short8 bh[8], bl[8];
        #pragma unroll
        for (int j = 0; j < 8; ++j) {
            size_t off = (size_t)(col0 + j * 16 + fr) * EMB + koff;
            bh[j] = *(const short8*)(Hthi + off);
            bl[j] = *(const short8*)(Htlo + off);
        }
        #pragma unroll
        for (int i = 0; i < 2; ++i)
            #pragma unroll
            for (int j = 0; j < 8; ++j) {
                acc[i][j] = __builtin_amdgcn_mfma_f32_16x16x32_bf16(ah[i], bh[j], acc[i][j], 0, 0, 0);
                acc[i][j] = __builtin_amdgcn_mfma_f32_16x16x32_bf16(ah[i], bl[j], acc[i][j], 0, 0, 0);
                acc[i][j] = __builtin_amdgcn_mfma_f32_16x16x32_bf16(al[i], bh[j], acc[i][j], 0, 0, 0);
            }
    }
    #pragma unroll
    for (int i = 0; i < 2; ++i) {
        int rbase = row0 + i * 16 + (lane >> 4) * 4;
        #pragma unroll
        for (int j = 0; j < 8; ++j) {
            int c = col0 + j * 16 + (lane & 15);
            #pragma unroll
            for (int r = 0; r < 4; ++r) {
                if (rbase + r < N_NODES)
                    C[(size_t)(rbase + r) * EMB + c] = acc[i][j][r];
            }
        }
    }
}

// ---------------------------------------------------------------- CSR build
__global__ void hist_k(const int* __restrict__ src, int* __restrict__ cnt) {
    int e = blockIdx.x * 256 + threadIdx.x;
    if (e < N_EDGES) atomicAdd(&cnt[src[e]], 1);
}

__global__ __launch_bounds__(1024) void scan_k(const int* __restrict__ cnt,
                                               int* __restrict__ row_start) {
    __shared__ int wsum[16];
    __shared__ int carry_s;
    const int t = threadIdx.x;
    const int lane = t & 63, wid = t >> 6;
    if (t == 0) carry_s = 0;
    __syncthreads();
    for (int base = 0; base < N_NODES; base += 1024) {
        int idx = base + t;
        int v = (idx < N_NODES) ? cnt[idx] : 0;
        int incl = v;
        #pragma unroll
        for (int off = 1; off < 64; off <<= 1) {
            int u = __shfl_up(incl, off);
            if (lane >= off) incl += u;
        }
        if (lane == 63) wsum[wid] = incl;
        __syncthreads();
        if (t < 16) {
            int wv = wsum[t];
            #pragma unroll
            for (int off = 1; off < 16; off <<= 1) {
                int u = __shfl_up(wv, off);
                if (t >= off) wv += u;
            }
            wsum[t] = wv;
        }
        __syncthreads();
        int woff = (wid > 0) ? wsum[wid - 1] : 0;
        incl += woff;
        int c = carry_s;
        if (idx < N_NODES) row_start[idx] = c + incl - v;
        __syncthreads();
        if (t == 1023) carry_s = c + incl;
        __syncthreads();
    }
    if (t == 0) row_start[N_NODES] = carry_s;
}

__global__ void place_edges(const int* __restrict__ src, const int* __restrict__ dst,
                            const float* __restrict__ val, int* __restrict__ cursor,
                            int* __restrict__ dst_s, float* __restrict__ val_s) {
    int e = blockIdx.x * 256 + threadIdx.x;
    if (e >= N_EDGES) return;
    int pos = atomicAdd(&cursor[src[e]], 1);
    dst_s[pos] = dst[e];
    val_s[pos] = val[e];
}

// ------------------------------------- X[row] = tanh( sum_e val * support[dst] )
__global__ __launch_bounds__(256) void spmm_tanh(const int* __restrict__ row_start,
                                                 const int* __restrict__ dst_s,
                                                 const float* __restrict__ val_s,
                                                 const float* __restrict__ support,
                                                 float* __restrict__ X) {
    int row = blockIdx.x * 4 + (threadIdx.x >> 6);
    if (row >= N_NODES) return;
    int lane = threadIdx.x & 63;
    int beg = row_start[row], end = row_start[row + 1];
    float4 acc = make_float4(0.f, 0.f, 0.f, 0.f);
    for (int i = beg; i < end; ++i) {
        int d = dst_s[i];
        float v = val_s[i];
        float4 x = *(const float4*)(support + (size_t)d * EMB + lane * 4);
        acc.x = fmaf(v, x.x, acc.x);
        acc.y = fmaf(v, x.y, acc.y);
        acc.z = fmaf(v, x.z, acc.z);
        acc.w = fmaf(v, x.w, acc.w);
    }
    float4 o;
    o.x = tanhf(acc.x); o.y = tanhf(acc.y); o.z = tanhf(acc.z); o.w = tanhf(acc.w);
    *(float4*)(X + (size_t)row * EMB + lane * 4) = o;
}

// ---------------------------------------------------------------- X fp32 -> bf16
__global__ void cvt_X(const float* __restrict__ X, short* __restrict__ Xb) {
    int i = (blockIdx.x * 256 + threadIdx.x) * 4;   // NODE_F elements total
    float4 v = *(const float4*)(X + i);
    short4 o;
    o.x = f2bf(v.x); o.y = f2bf(v.y); o.z = f2bf(v.z); o.w = f2bf(v.w);
    *(short4*)(Xb + i) = o;
}

// ---------------------------------------------------------------- hr = X[e1] * X[r+N_ENT]
__global__ void hr_k(const float* __restrict__ X, const int* __restrict__ e1,
                     const int* __restrict__ ri, float* __restrict__ hr) {
    int b = blockIdx.x, f = threadIdx.x;
    float h = X[(size_t)e1[b] * EMB + f];
    float r = X[((size_t)ri[b] + N_ENT) * EMB + f];
    hr[b * EMB + f] = h * r;
}

// ---------------------------------------------------------------- batchnorm stats
__global__ __launch_bounds__(256) void bn_stats(const float* __restrict__ hr,
                                                float* __restrict__ mean,
                                                float* __restrict__ var) {
    int f = blockIdx.x, t = threadIdx.x;
    float s = 0.f, sq = 0.f;
    for (int b = t; b < BATCH; b += 256) {
        float v = hr[b * EMB + f];
        s += v; sq += v * v;
    }
    #pragma unroll
    for (int off = 32; off > 0; off >>= 1) {
        s  += __shfl_down(s, off);
        sq += __shfl_down(sq, off);
    }
    __shared__ float ss[4], sqs[4];
    int w = t >> 6;
    if ((t & 63) == 0) { ss[w] = s; sqs[w] = sq; }
    __syncthreads();
    if (t == 0) {
        s  = ss[0] + ss[1] + ss[2] + ss[3];
        sq = sqs[0] + sqs[1] + sqs[2] + sqs[3];
        float m = s * (1.f / BATCH);
        mean[f] = m;
        var[f] = sq * (1.f / BATCH) - m * m;
    }
}

// --------------------------------------------- batchnorm apply + hi/lo bf16 split
__global__ void bn_apply_split(const float* __restrict__ hr, const float* __restrict__ mean,
                               const float* __restrict__ var, const float* __restrict__ gamma,
                               const float* __restrict__ beta,
                               short* __restrict__ hi, short* __restrict__ lo) {
    int idx = blockIdx.x * 256 + threadIdx.x;   // 262144
    int f = idx & 255;
    float inv = rsqrtf(var[f] + BN_EPS);
    float v = (hr[idx] - mean[f]) * inv * gamma[f] + beta[f];
    short h = f2bf(v);
    hi[idx] = h;
    lo[idx] = f2bf(v - bf2f(h));
}

// ------------- out = sigmoid((hr_hi+hr_lo) @ Xb[:N_ENT]^T)  [1024 x 40000], MFMA
// grid.x = M blocks (16, fastest-varying -> co-resident blocks share B panel)
// grid.y = N blocks (250); nontemporal out stores keep Xb L3-resident
__global__ __launch_bounds__(256) void score_gemm_mfma(const short* __restrict__ hrhi,
                                                       const short* __restrict__ hrlo,
                                                       const short* __restrict__ Xb,
                                                       float* __restrict__ out) {
    const int wid  = threadIdx.x >> 6;
    const int lane = threadIdx.x & 63;
    const int wr = wid >> 1, wc = wid & 1;
    const int row0 = blockIdx.x * 64 + wr * 32;
    const int col0 = blockIdx.y * 160 + wc * 80;
    const int fr = lane & 15;
    const int kg = lane >> 4;
    f32x4 acc[2][5] = {};
    #pragma unroll 2
    for (int kb = 0; kb < 8; ++kb) {
        const int koff = kb * 32 + kg * 8;
        short8 a_hi[2], a_lo[2], b[5];
        #pragma unroll
        for (int i = 0; i < 2; ++i) {
            size_t off = (size_t)(row0 + i * 16 + fr) * EMB + koff;
            a_hi[i] = *(const short8*)(hrhi + off);
            a_lo[i] = *(const short8*)(hrlo + off);
        }
        #pragma unroll
        for (int j = 0; j < 5; ++j)
            b[j] = *(const short8*)(Xb + (size_t)(col0 + j * 16 + fr) * EMB + koff);
        #pragma unroll
        for (int i = 0; i < 2; ++i)
            #pragma unroll
            for (int j = 0; j < 5; ++j) {
                acc[i][j] = __builtin_amdgcn_mfma_f32_16x16x32_bf16(a_hi[i], b[j], acc[i][j], 0, 0, 0);
                acc[i][j] = __builtin_amdgcn_mfma_f32_16x16x32_bf16(a_lo[i], b[j], acc[i][j], 0, 0, 0);
            }
    }
    #pragma unroll
    for (int i = 0; i < 2; ++i) {
        int rbase = row0 + i * 16 + (lane >> 4) * 4;
        #pragma unroll
        for (int j = 0; j < 5; ++j) {
            int c = col0 + j * 16 + (lane & 15);
            #pragma unroll
            for (int r = 0; r < 4; ++r) {
                float s = 1.f / (1.f + __expf(-acc[i][j][r]));
                __builtin_nontemporal_store(s, out + (size_t)(rbase + r) * N_ENT + c);
            }
        }
    }
}

extern "C" void kernel_launch(void* const* d_in, const int* in_sizes, int n_in,
                              void* d_out, int out_size, void* d_ws, size_t ws_size,
                              hipStream_t stream) {
    const int*   e1    = (const int*)d_in[0];
    const int*   ri    = (const int*)d_in[1];
    const float* emb   = (const float*)d_in[3];
    const float* qw    = (const float*)d_in[4];
    const int*   esrc  = (const int*)d_in[5];
    const int*   edst  = (const int*)d_in[6];
    const float* evalv = (const float*)d_in[7];
    const float* gamma = (const float*)d_in[8];
    const float* beta  = (const float*)d_in[9];
    float* out = (float*)d_out;

    const size_t NODE_F = (size_t)N_NODES * EMB;   // 10,368,000
    float* support   = (float*)d_ws;               // NODE_F
    float* X         = support + NODE_F;           // NODE_F
    float* hr        = X + NODE_F;                 // 262144
    float* mean      = hr + 262144;                // 256
    float* var       = mean + 256;                 // 256
    int*   row_start = (int*)(var + 256);          // N_NODES+1
    int*   cnt       = row_start + (N_NODES + 1);  // N_NODES (cursor)
    int*   dst_s     = cnt + N_NODES;              // N_EDGES
    float* val_s     = (float*)(dst_s + N_EDGES);  // N_EDGES
    short* hrhi      = (short*)(val_s + N_EDGES);  // 262144 shorts
    short* hrlo      = hrhi + 262144;              // 262144 shorts
    short* Hthi      = hrlo + 262144;              // 65536 shorts
    short* Htlo      = Hthi + 65536;               // 65536 shorts
    // aliases (lifetime-disjoint):
    short* ehi       = (short*)X;                  // dead once spmm_tanh writes X
    short* elo       = ehi + NODE_F;
    short* Xb        = (short*)support;            // support dead after spmm_tanh

    // CSR build (no fp atomics anywhere)
    hipMemsetAsync(cnt, 0, N_NODES * sizeof(int), stream);
    hist_k<<<(N_EDGES + 255) / 256, 256, 0, stream>>>(esrc, cnt);
    scan_k<<<1, 1024, 0, stream>>>(cnt, row_start);
    hipMemcpyAsync(cnt, row_start, N_NODES * sizeof(int), hipMemcpyDeviceToDevice, stream);

    build_hamilton_t<<<256, 256, 0, stream>>>(qw, Hthi, Htlo);
    cvt_emb<<<(int)(NODE_F / 1024), 256, 0, stream>>>(emb, ehi, elo);
    support_mfma<<<633, 256, 0, stream>>>(ehi, elo, Hthi, Htlo, support);

    place_edges<<<(N_EDGES + 255) / 256, 256, 0, stream>>>(esrc, edst, evalv, cnt, dst_s, val_s);
    spmm_tanh<<<N_NODES / 4, 256, 0, stream>>>(row_start, dst_s, val_s, support, X);
    cvt_X<<<(int)(NODE_F / 1024), 256, 0, stream>>>(X, Xb);

    hr_k<<<BATCH, 256, 0, stream>>>(X, e1, ri, hr);
    bn_stats<<<EMB, 256, 0, stream>>>(hr, mean, var);
    bn_apply_split<<<1024, 256, 0, stream>>>(hr, mean, var, gamma, beta, hrhi, hrlo);
    score_gemm_mfma<<<dim3(16, 250), 256, 0, stream>>>(hrhi, hrlo, Xb, out);
}

// Round 7
// 377.576 us; speedup vs baseline: 6.8814x; 1.1992x over previous
//
#include <hip/hip_runtime.h>
#include <math.h>

#define N_ENT 40000
#define N_NODES 40500
#define EMB 256
#define N_EDGES 648000
#define BATCH 1024
#define BN_EPS 1e-5f

typedef __attribute__((ext_vector_type(8))) short short8;
typedef __attribute__((ext_vector_type(4))) float f32x4;

__device__ inline short f2bf(float f) {
    unsigned u = __float_as_uint(f);
    return (short)((u + 0x7FFFu + ((u >> 16) & 1u)) >> 16);
}
__device__ inline float bf2f(short s) {
    return __uint_as_float(((unsigned)(unsigned short)s) << 16);
}

__device__ __forceinline__ void gl_lds16(const void* g, void* l) {
    __builtin_amdgcn_global_load_lds(
        (const __attribute__((address_space(1))) void*)g,
        (__attribute__((address_space(3))) void*)l, 16, 0, 0);
}

// ------------------------------------------- hamilton, transposed, bf16 hi/lo
__global__ void build_hamilton_t(const float* __restrict__ qw,
                                 short* __restrict__ Hthi, short* __restrict__ Htlo) {
    int idx = blockIdx.x * 256 + threadIdx.x;   // 65536; idx = o*256 + i
    int o = idx >> 8, i = idx & 255;
    int p = i >> 6, i0 = i & 63;
    int q = o >> 6, o0 = o & 63;
    const int   ctab[16] = {0,1,2,3, 1,0,3,2, 2,3,0,1, 3,2,1,0};
    const float stab[16] = {1.f,1.f,1.f,1.f, -1.f,1.f,1.f,-1.f, -1.f,-1.f,1.f,1.f, -1.f,1.f,-1.f,1.f};
    float v = stab[p*4+q] * qw[i0*EMB + ctab[p*4+q]*64 + o0];
    short h = f2bf(v);
    Hthi[idx] = h;
    Htlo[idx] = f2bf(v - bf2f(h));
}

// ---------------------------------------------------------------- emb -> bf16 hi/lo
__global__ void cvt_emb(const float* __restrict__ e, short* __restrict__ hi,
                        short* __restrict__ lo) {
    size_t i = (size_t)(blockIdx.x * 256 + threadIdx.x) * 4;
    float4 v = *(const float4*)(e + i);
    short4 h, l;
    h.x = f2bf(v.x); l.x = f2bf(v.x - bf2f(h.x));
    h.y = f2bf(v.y); l.y = f2bf(v.y - bf2f(h.y));
    h.z = f2bf(v.z); l.z = f2bf(v.z - bf2f(h.z));
    h.w = f2bf(v.w); l.w = f2bf(v.w - bf2f(h.w));
    *(short4*)(hi + i) = h;
    *(short4*)(lo + i) = l;
}

// ---------------------- support = emb @ H via 3-term hi/lo MFMA (~fp32 exact)
__global__ __launch_bounds__(256) void support_mfma(const short* __restrict__ ehi,
                                                    const short* __restrict__ elo,
                                                    const short* __restrict__ Hthi,
                                                    const short* __restrict__ Htlo,
                                                    float* __restrict__ C) {
    const int wid  = threadIdx.x >> 6;
    const int lane = threadIdx.x & 63;
    const int wr = wid >> 1, wc = wid & 1;
    const int row0 = blockIdx.x * 64 + wr * 32;
    const int col0 = wc * 128;
    const int fr = lane & 15;
    const int kg = lane >> 4;
    f32x4 acc[2][8] = {};
    for (int kb = 0; kb < 8; ++kb) {
        const int koff = kb * 32 + kg * 8;
        short8 ah[2], al[2];
        #pragma unroll
        for (int i = 0; i < 2; ++i) {
            int r = row0 + i * 16 + fr;
            if (r > N_NODES - 1) r = N_NODES - 1;
            size_t off = (size_t)r * EMB + koff;
            ah[i] = *(const short8*)(ehi + off);
            al[i] = *(const short8*)(elo + off);
        }
        short8 bh[8], bl[8];
        #pragma unroll
        for (int j = 0; j < 8; ++j) {
            size_t off = (size_t)(col0 + j * 16 + fr) * EMB + koff;
            bh[j] = *(const short8*)(Hthi + off);
            bl[j] = *(const short8*)(Htlo + off);
        }
        #pragma unroll
        for (int i = 0; i < 2; ++i)
            #pragma unroll
            for (int j = 0; j < 8; ++j) {
                acc[i][j] = __builtin_amdgcn_mfma_f32_16x16x32_bf16(ah[i], bh[j], acc[i][j], 0, 0, 0);
                acc[i][j] = __builtin_amdgcn_mfma_f32_16x16x32_bf16(ah[i], bl[j], acc[i][j], 0, 0, 0);
                acc[i][j] = __builtin_amdgcn_mfma_f32_16x16x32_bf16(al[i], bh[j], acc[i][j], 0, 0, 0);
            }
    }
    #pragma unroll
    for (int i = 0; i < 2; ++i) {
        int rbase = row0 + i * 16 + (lane >> 4) * 4;
        #pragma unroll
        for (int j = 0; j < 8; ++j) {
            int c = col0 + j * 16 + (lane & 15);
            #pragma unroll
            for (int r = 0; r < 4; ++r) {
                if (rbase + r < N_NODES)
                    C[(size_t)(rbase + r) * EMB + c] = acc[i][j][r];
            }
        }
    }
}

// ---------------------------------------------------------------- CSR build
__global__ void hist_k(const int* __restrict__ src, int* __restrict__ cnt) {
    int e = blockIdx.x * 256 + threadIdx.x;
    if (e < N_EDGES) atomicAdd(&cnt[src[e]], 1);
}

__global__ __launch_bounds__(1024) void scan_k(const int* __restrict__ cnt,
                                               int* __restrict__ row_start) {
    __shared__ int wsum[16];
    __shared__ int carry_s;
    const int t = threadIdx.x;
    const int lane = t & 63, wid = t >> 6;
    if (t == 0) carry_s = 0;
    __syncthreads();
    for (int base = 0; base < N_NODES; base += 1024) {
        int idx = base + t;
        int v = (idx < N_NODES) ? cnt[idx] : 0;
        int incl = v;
        #pragma unroll
        for (int off = 1; off < 64; off <<= 1) {
            int u = __shfl_up(incl, off);
            if (lane >= off) incl += u;
        }
        if (lane == 63) wsum[wid] = incl;
        __syncthreads();
        if (t < 16) {
            int wv = wsum[t];
            #pragma unroll
            for (int off = 1; off < 16; off <<= 1) {
                int u = __shfl_up(wv, off);
                if (t >= off) wv += u;
            }
            wsum[t] = wv;
        }
        __syncthreads();
        int woff = (wid > 0) ? wsum[wid - 1] : 0;
        incl += woff;
        int c = carry_s;
        if (idx < N_NODES) row_start[idx] = c + incl - v;
        __syncthreads();
        if (t == 1023) carry_s = c + incl;
        __syncthreads();
    }
    if (t == 0) row_start[N_NODES] = carry_s;
}

__global__ void place_edges(const int* __restrict__ src, const int* __restrict__ dst,
                            const float* __restrict__ val, int* __restrict__ cursor,
                            int* __restrict__ dst_s, float* __restrict__ val_s) {
    int e = blockIdx.x * 256 + threadIdx.x;
    if (e >= N_EDGES) return;
    int pos = atomicAdd(&cursor[src[e]], 1);
    dst_s[pos] = dst[e];
    val_s[pos] = val[e];
}

// ------------------------------------- X[row] = tanh( sum_e val * support[dst] )
__global__ __launch_bounds__(256) void spmm_tanh(const int* __restrict__ row_start,
                                                 const int* __restrict__ dst_s,
                                                 const float* __restrict__ val_s,
                                                 const float* __restrict__ support,
                                                 float* __restrict__ X) {
    int row = blockIdx.x * 4 + (threadIdx.x >> 6);
    if (row >= N_NODES) return;
    int lane = threadIdx.x & 63;
    int beg = row_start[row], end = row_start[row + 1];
    float4 acc = make_float4(0.f, 0.f, 0.f, 0.f);
    for (int i = beg; i < end; ++i) {
        int d = dst_s[i];
        float v = val_s[i];
        float4 x = *(const float4*)(support + (size_t)d * EMB + lane * 4);
        acc.x = fmaf(v, x.x, acc.x);
        acc.y = fmaf(v, x.y, acc.y);
        acc.z = fmaf(v, x.z, acc.z);
        acc.w = fmaf(v, x.w, acc.w);
    }
    float4 o;
    o.x = tanhf(acc.x); o.y = tanhf(acc.y); o.z = tanhf(acc.z); o.w = tanhf(acc.w);
    *(float4*)(X + (size_t)row * EMB + lane * 4) = o;
}

// ------------------- X fp32 -> bf16 (separate pass: Xb aliases dead support!)
__global__ void cvt_X(const float* __restrict__ X, short* __restrict__ Xb) {
    int i = (blockIdx.x * 256 + threadIdx.x) * 4;
    float4 v = *(const float4*)(X + i);
    short4 o;
    o.x = f2bf(v.x); o.y = f2bf(v.y); o.z = f2bf(v.z); o.w = f2bf(v.w);
    *(short4*)(Xb + i) = o;
}

// ---------------------------------------------------------------- hr = X[e1] * X[r+N_ENT]
__global__ void hr_k(const float* __restrict__ X, const int* __restrict__ e1,
                     const int* __restrict__ ri, float* __restrict__ hr) {
    int b = blockIdx.x, f = threadIdx.x;
    float h = X[(size_t)e1[b] * EMB + f];
    float r = X[((size_t)ri[b] + N_ENT) * EMB + f];
    hr[b * EMB + f] = h * r;
}

// ---------------------------------------------------------------- batchnorm stats
__global__ __launch_bounds__(256) void bn_stats(const float* __restrict__ hr,
                                                float* __restrict__ mean,
                                                float* __restrict__ var) {
    int f = blockIdx.x, t = threadIdx.x;
    float s = 0.f, sq = 0.f;
    for (int b = t; b < BATCH; b += 256) {
        float v = hr[b * EMB + f];
        s += v; sq += v * v;
    }
    #pragma unroll
    for (int off = 32; off > 0; off >>= 1) {
        s  += __shfl_down(s, off);
        sq += __shfl_down(sq, off);
    }
    __shared__ float ss[4], sqs[4];
    int w = t >> 6;
    if ((t & 63) == 0) { ss[w] = s; sqs[w] = sq; }
    __syncthreads();
    if (t == 0) {
        s  = ss[0] + ss[1] + ss[2] + ss[3];
        sq = sqs[0] + sqs[1] + sqs[2] + sqs[3];
        float m = s * (1.f / BATCH);
        mean[f] = m;
        var[f] = sq * (1.f / BATCH) - m * m;
    }
}

// --------------------------------------------- batchnorm apply + hi/lo bf16 split
__global__ void bn_apply_split(const float* __restrict__ hr, const float* __restrict__ mean,
                               const float* __restrict__ var, const float* __restrict__ gamma,
                               const float* __restrict__ beta,
                               short* __restrict__ hi, short* __restrict__ lo) {
    int idx = blockIdx.x * 256 + threadIdx.x;   // 262144
    int f = idx & 255;
    float inv = rsqrtf(var[f] + BN_EPS);
    float v = (hr[idx] - mean[f]) * inv * gamma[f] + beta[f];
    short h = f2bf(v);
    hi[idx] = h;
    lo[idx] = f2bf(v - bf2f(h));
}

// ------------- out = sigmoid((hr_hi+hr_lo) @ Xb[:N_ENT]^T), m97-style LDS GEMM
// block 64(M) x 128(N), BK=32, 4 waves 2x2 (wave 32x64 = 2x4 frags, 16 MFMA/step)
// A LDS tile = [128][32] bf16: rows 0-63 = hr_hi, rows 64-127 = hr_lo
// B LDS tile = [128][32] bf16: 128 entity rows of Xb
// epilogue: sigmoid -> LDS fp32 [64][132] -> coalesced float4 NT stores
__global__ __launch_bounds__(256) void score_v2(const short* __restrict__ hrhi,
                                                const short* __restrict__ hrlo,
                                                const short* __restrict__ Xb,
                                                float* __restrict__ out) {
    __shared__ char smem[64 * 132 * 4];       // 33.8 KB (>= 16 KB A+B)
    short* As = (short*)smem;                 // [128][32]
    short* Bs = As + 4096;                    // [128][32]
    float* Ep = (float*)smem;                 // [64][132]

    const int tid  = threadIdx.x;
    const int wid  = tid >> 6;
    const int lane = tid & 63;
    const int wr = wid >> 1, wc = wid & 1;
    const int row0 = blockIdx.x * 64;         // M block (16)
    const int col0 = blockIdx.y * 128;        // N block (313)
    const int fr = lane & 15;
    const int kg = lane >> 4;
    const int lrow = lane >> 2;               // staging: row within 16-row chunk
    const int lchk = (lane & 3) * 8;          // staging: short offset within 64B row

    f32x4 acc[2][4] = {};

    for (int kb = 0; kb < 8; ++kb) {
        const int koff = kb * 32;
        // ---- stage A (2 chunks/wave) + B (2 chunks/wave) via global_load_lds
        {
            int c0 = wid * 2;
            #pragma unroll
            for (int c = 0; c < 2; ++c) {
                int ch = c0 + c;                       // 0..7
                int lr = ch * 16 + lrow;               // lds row 0..127
                const short* srcA = ((lr < 64) ? hrhi : hrlo)
                                  + (size_t)(row0 + (lr & 63)) * EMB + koff + lchk;
                gl_lds16(srcA, (char*)As + ch * 1024);
                int gc = col0 + lr;
                if (gc > N_ENT - 1) gc = N_ENT - 1;
                const short* srcB = Xb + (size_t)gc * EMB + koff + lchk;
                gl_lds16(srcB, (char*)Bs + ch * 1024);
            }
        }
        __syncthreads();
        // ---- fragments from LDS + MFMA
        short8 ahi[2], alo[2], b[4];
        #pragma unroll
        for (int i = 0; i < 2; ++i) {
            int r = wr * 32 + i * 16 + fr;
            ahi[i] = *(const short8*)&As[r * 32 + kg * 8];
            alo[i] = *(const short8*)&As[(64 + r) * 32 + kg * 8];
        }
        #pragma unroll
        for (int j = 0; j < 4; ++j) {
            int r = wc * 64 + j * 16 + fr;
            b[j] = *(const short8*)&Bs[r * 32 + kg * 8];
        }
        #pragma unroll
        for (int i = 0; i < 2; ++i)
            #pragma unroll
            for (int j = 0; j < 4; ++j) {
                acc[i][j] = __builtin_amdgcn_mfma_f32_16x16x32_bf16(ahi[i], b[j], acc[i][j], 0, 0, 0);
                acc[i][j] = __builtin_amdgcn_mfma_f32_16x16x32_bf16(alo[i], b[j], acc[i][j], 0, 0, 0);
            }
        __syncthreads();
    }

    // ---- epilogue: sigmoid -> LDS -> coalesced NT float4 stores
    #pragma unroll
    for (int i = 0; i < 2; ++i) {
        int rl = wr * 32 + i * 16 + (lane >> 4) * 4;
        #pragma unroll
        for (int j = 0; j < 4; ++j) {
            int cl = wc * 64 + j * 16 + (lane & 15);
            #pragma unroll
            for (int r = 0; r < 4; ++r)
                Ep[(rl + r) * 132 + cl] = 1.f / (1.f + __expf(-acc[i][j][r]));
        }
    }
    __syncthreads();
    #pragma unroll
    for (int it = 0; it < 8; ++it) {
        int idx = it * 256 + tid;
        int row = idx >> 5;
        int c4 = (idx & 31) << 2;
        f32x4 v = *(const f32x4*)&Ep[row * 132 + c4];
        int gc = col0 + c4;
        if (gc < N_ENT)
            __builtin_nontemporal_store(v, (f32x4*)(out + (size_t)(row0 + row) * N_ENT + gc));
    }
}

extern "C" void kernel_launch(void* const* d_in, const int* in_sizes, int n_in,
                              void* d_out, int out_size, void* d_ws, size_t ws_size,
                              hipStream_t stream) {
    const int*   e1    = (const int*)d_in[0];
    const int*   ri    = (const int*)d_in[1];
    const float* emb   = (const float*)d_in[3];
    const float* qw    = (const float*)d_in[4];
    const int*   esrc  = (const int*)d_in[5];
    const int*   edst  = (const int*)d_in[6];
    const float* evalv = (const float*)d_in[7];
    const float* gamma = (const float*)d_in[8];
    const float* beta  = (const float*)d_in[9];
    float* out = (float*)d_out;

    const size_t NODE_F = (size_t)N_NODES * EMB;   // 10,368,000
    float* support   = (float*)d_ws;               // NODE_F
    float* X         = support + NODE_F;           // NODE_F
    float* hr        = X + NODE_F;                 // 262144
    float* mean      = hr + 262144;                // 256
    float* var       = mean + 256;                 // 256
    int*   row_start = (int*)(var + 256);          // N_NODES+1
    int*   cnt       = row_start + (N_NODES + 1);  // N_NODES (cursor)
    int*   dst_s     = cnt + N_NODES;              // N_EDGES
    float* val_s     = (float*)(dst_s + N_EDGES);  // N_EDGES
    short* hrhi      = (short*)(val_s + N_EDGES);  // 262144 shorts
    short* hrlo      = hrhi + 262144;              // 262144 shorts
    short* Hthi      = hrlo + 262144;              // 65536 shorts
    short* Htlo      = Hthi + 65536;               // 65536 shorts
    // aliases (lifetime-disjoint):
    short* ehi       = (short*)X;                  // dead once spmm_tanh writes X
    short* elo       = ehi + NODE_F;
    short* Xb        = (short*)support;            // written ONLY by cvt_X, after
                                                   // spmm_tanh fully consumed support

    // CSR build (no fp atomics anywhere)
    hipMemsetAsync(cnt, 0, N_NODES * sizeof(int), stream);
    hist_k<<<(N_EDGES + 255) / 256, 256, 0, stream>>>(esrc, cnt);
    scan_k<<<1, 1024, 0, stream>>>(cnt, row_start);
    hipMemcpyAsync(cnt, row_start, N_NODES * sizeof(int), hipMemcpyDeviceToDevice, stream);

    build_hamilton_t<<<256, 256, 0, stream>>>(qw, Hthi, Htlo);
    cvt_emb<<<(int)(NODE_F / 1024), 256, 0, stream>>>(emb, ehi, elo);
    support_mfma<<<633, 256, 0, stream>>>(ehi, elo, Hthi, Htlo, support);

    place_edges<<<(N_EDGES + 255) / 256, 256, 0, stream>>>(esrc, edst, evalv, cnt, dst_s, val_s);
    spmm_tanh<<<N_NODES / 4, 256, 0, stream>>>(row_start, dst_s, val_s, support, X);
    cvt_X<<<(int)(NODE_F / 1024), 256, 0, stream>>>(X, Xb);

    hr_k<<<BATCH, 256, 0, stream>>>(X, e1, ri, hr);
    bn_stats<<<EMB, 256, 0, stream>>>(hr, mean, var);
    bn_apply_split<<<1024, 256, 0, stream>>>(hr, mean, var, gamma, beta, hrhi, hrlo);
    score_v2<<<dim3(16, 313), 256, 0, stream>>>(hrhi, hrlo, Xb, out);
}

// Round 8
// 349.349 us; speedup vs baseline: 7.4374x; 1.0808x over previous
//
#include <hip/hip_runtime.h>
#include <math.h>

#define N_ENT 40000
#define N_NODES 40500
#define EMB 256
#define N_EDGES 648000
#define BATCH 1024
#define BN_EPS 1e-5f

typedef __attribute__((ext_vector_type(8))) short short8;
typedef __attribute__((ext_vector_type(4))) float f32x4;

__device__ inline short f2bf(float f) {
    unsigned u = __float_as_uint(f);
    return (short)((u + 0x7FFFu + ((u >> 16) & 1u)) >> 16);
}
__device__ inline float bf2f(short s) {
    return __uint_as_float(((unsigned)(unsigned short)s) << 16);
}

__device__ __forceinline__ void gl_lds16(const void* g, void* l) {
    __builtin_amdgcn_global_load_lds(
        (const __attribute__((address_space(1))) void*)g,
        (__attribute__((address_space(3))) void*)l, 16, 0, 0);
}

// ------------------------------------------- hamilton, transposed, bf16 hi/lo
__global__ void build_hamilton_t(const float* __restrict__ qw,
                                 short* __restrict__ Hthi, short* __restrict__ Htlo) {
    int idx = blockIdx.x * 256 + threadIdx.x;   // 65536; idx = o*256 + i
    int o = idx >> 8, i = idx & 255;
    int p = i >> 6, i0 = i & 63;
    int q = o >> 6, o0 = o & 63;
    const int   ctab[16] = {0,1,2,3, 1,0,3,2, 2,3,0,1, 3,2,1,0};
    const float stab[16] = {1.f,1.f,1.f,1.f, -1.f,1.f,1.f,-1.f, -1.f,-1.f,1.f,1.f, -1.f,1.f,-1.f,1.f};
    float v = stab[p*4+q] * qw[i0*EMB + ctab[p*4+q]*64 + o0];
    short h = f2bf(v);
    Hthi[idx] = h;
    Htlo[idx] = f2bf(v - bf2f(h));
}

// ---------------------------------------------------------------- emb -> bf16 hi/lo
__global__ void cvt_emb(const float* __restrict__ e, short* __restrict__ hi,
                        short* __restrict__ lo) {
    size_t i = (size_t)(blockIdx.x * 256 + threadIdx.x) * 4;
    float4 v = *(const float4*)(e + i);
    short4 h, l;
    h.x = f2bf(v.x); l.x = f2bf(v.x - bf2f(h.x));
    h.y = f2bf(v.y); l.y = f2bf(v.y - bf2f(h.y));
    h.z = f2bf(v.z); l.z = f2bf(v.z - bf2f(h.z));
    h.w = f2bf(v.w); l.w = f2bf(v.w - bf2f(h.w));
    *(short4*)(hi + i) = h;
    *(short4*)(lo + i) = l;
}

// ----- support = emb @ H via 3-term hi/lo MFMA (~fp32 exact), stored as bf16
__global__ __launch_bounds__(256) void support_mfma(const short* __restrict__ ehi,
                                                    const short* __restrict__ elo,
                                                    const short* __restrict__ Hthi,
                                                    const short* __restrict__ Htlo,
                                                    short* __restrict__ Cb) {
    const int wid  = threadIdx.x >> 6;
    const int lane = threadIdx.x & 63;
    const int wr = wid >> 1, wc = wid & 1;
    const int row0 = blockIdx.x * 64 + wr * 32;
    const int col0 = wc * 128;
    const int fr = lane & 15;
    const int kg = lane >> 4;
    f32x4 acc[2][8] = {};
    for (int kb = 0; kb < 8; ++kb) {
        const int koff = kb * 32 + kg * 8;
        short8 ah[2], al[2];
        #pragma unroll
        for (int i = 0; i < 2; ++i) {
            int r = row0 + i * 16 + fr;
            if (r > N_NODES - 1) r = N_NODES - 1;
            size_t off = (size_t)r * EMB + koff;
            ah[i] = *(const short8*)(ehi + off);
            al[i] = *(const short8*)(elo + off);
        }
        short8 bh[8], bl[8];
        #pragma unroll
        for (int j = 0; j < 8; ++j) {
            size_t off = (size_t)(col0 + j * 16 + fr) * EMB + koff;
            bh[j] = *(const short8*)(Hthi + off);
            bl[j] = *(const short8*)(Htlo + off);
        }
        #pragma unroll
        for (int i = 0; i < 2; ++i)
            #pragma unroll
            for (int j = 0; j < 8; ++j) {
                acc[i][j] = __builtin_amdgcn_mfma_f32_16x16x32_bf16(ah[i], bh[j], acc[i][j], 0, 0, 0);
                acc[i][j] = __builtin_amdgcn_mfma_f32_16x16x32_bf16(ah[i], bl[j], acc[i][j], 0, 0, 0);
                acc[i][j] = __builtin_amdgcn_mfma_f32_16x16x32_bf16(al[i], bh[j], acc[i][j], 0, 0, 0);
            }
    }
    #pragma unroll
    for (int i = 0; i < 2; ++i) {
        int rbase = row0 + i * 16 + (lane >> 4) * 4;
        #pragma unroll
        for (int j = 0; j < 8; ++j) {
            int c = col0 + j * 16 + (lane & 15);
            #pragma unroll
            for (int r = 0; r < 4; ++r) {
                if (rbase + r < N_NODES)
                    Cb[(size_t)(rbase + r) * EMB + c] = f2bf(acc[i][j][r]);
            }
        }
    }
}

// ---------------------------------------------------------------- CSR build
__global__ void hist_k(const int* __restrict__ src, int* __restrict__ cnt) {
    int e = blockIdx.x * 256 + threadIdx.x;
    if (e < N_EDGES) atomicAdd(&cnt[src[e]], 1);
}

__global__ __launch_bounds__(1024) void scan_k(const int* __restrict__ cnt,
                                               int* __restrict__ row_start) {
    __shared__ int wsum[16];
    __shared__ int carry_s;
    const int t = threadIdx.x;
    const int lane = t & 63, wid = t >> 6;
    if (t == 0) carry_s = 0;
    __syncthreads();
    for (int base = 0; base < N_NODES; base += 1024) {
        int idx = base + t;
        int v = (idx < N_NODES) ? cnt[idx] : 0;
        int incl = v;
        #pragma unroll
        for (int off = 1; off < 64; off <<= 1) {
            int u = __shfl_up(incl, off);
            if (lane >= off) incl += u;
        }
        if (lane == 63) wsum[wid] = incl;
        __syncthreads();
        if (t < 16) {
            int wv = wsum[t];
            #pragma unroll
            for (int off = 1; off < 16; off <<= 1) {
                int u = __shfl_up(wv, off);
                if (t >= off) wv += u;
            }
            wsum[t] = wv;
        }
        __syncthreads();
        int woff = (wid > 0) ? wsum[wid - 1] : 0;
        incl += woff;
        int c = carry_s;
        if (idx < N_NODES) row_start[idx] = c + incl - v;
        __syncthreads();
        if (t == 1023) carry_s = c + incl;
        __syncthreads();
    }
    if (t == 0) row_start[N_NODES] = carry_s;
}

__global__ void place_edges(const int* __restrict__ src, const int* __restrict__ dst,
                            const float* __restrict__ val, int* __restrict__ cursor,
                            int* __restrict__ dst_s, float* __restrict__ val_s) {
    int e = blockIdx.x * 256 + threadIdx.x;
    if (e >= N_EDGES) return;
    int pos = atomicAdd(&cursor[src[e]], 1);
    dst_s[pos] = dst[e];
    val_s[pos] = val[e];
}

// -------- X[row] = tanh( sum val*support_bf[dst] ); fused fp32 X + bf16 Xb out
// (Xb is a SEPARATE buffer — no alias with support_bf, fusion is race-free)
__global__ __launch_bounds__(256) void spmm_tanh(const int* __restrict__ row_start,
                                                 const int* __restrict__ dst_s,
                                                 const float* __restrict__ val_s,
                                                 const short* __restrict__ support_bf,
                                                 float* __restrict__ X,
                                                 short* __restrict__ Xb) {
    int row = blockIdx.x * 4 + (threadIdx.x >> 6);
    if (row >= N_NODES) return;
    int lane = threadIdx.x & 63;
    int beg = row_start[row], end = row_start[row + 1];
    float4 acc = make_float4(0.f, 0.f, 0.f, 0.f);
    for (int i = beg; i < end; ++i) {
        int d = dst_s[i];
        float v = val_s[i];
        short4 x = *(const short4*)(support_bf + (size_t)d * EMB + lane * 4);
        acc.x = fmaf(v, bf2f(x.x), acc.x);
        acc.y = fmaf(v, bf2f(x.y), acc.y);
        acc.z = fmaf(v, bf2f(x.z), acc.z);
        acc.w = fmaf(v, bf2f(x.w), acc.w);
    }
    float4 o;
    o.x = tanhf(acc.x); o.y = tanhf(acc.y); o.z = tanhf(acc.z); o.w = tanhf(acc.w);
    *(float4*)(X + (size_t)row * EMB + lane * 4) = o;
    short4 ob;
    ob.x = f2bf(o.x); ob.y = f2bf(o.y); ob.z = f2bf(o.z); ob.w = f2bf(o.w);
    *(short4*)(Xb + (size_t)row * EMB + lane * 4) = ob;
}

// ---------------------------------------------------------------- hr = X[e1] * X[r+N_ENT]
__global__ void hr_k(const float* __restrict__ X, const int* __restrict__ e1,
                     const int* __restrict__ ri, float* __restrict__ hr) {
    int b = blockIdx.x, f = threadIdx.x;
    float h = X[(size_t)e1[b] * EMB + f];
    float r = X[((size_t)ri[b] + N_ENT) * EMB + f];
    hr[b * EMB + f] = h * r;
}

// ---------------------------------------------------------------- batchnorm stats
__global__ __launch_bounds__(256) void bn_stats(const float* __restrict__ hr,
                                                float* __restrict__ mean,
                                                float* __restrict__ var) {
    int f = blockIdx.x, t = threadIdx.x;
    float s = 0.f, sq = 0.f;
    for (int b = t; b < BATCH; b += 256) {
        float v = hr[b * EMB + f];
        s += v; sq += v * v;
    }
    #pragma unroll
    for (int off = 32; off > 0; off >>= 1) {
        s  += __shfl_down(s, off);
        sq += __shfl_down(sq, off);
    }
    __shared__ float ss[4], sqs[4];
    int w = t >> 6;
    if ((t & 63) == 0) { ss[w] = s; sqs[w] = sq; }
    __syncthreads();
    if (t == 0) {
        s  = ss[0] + ss[1] + ss[2] + ss[3];
        sq = sqs[0] + sqs[1] + sqs[2] + sqs[3];
        float m = s * (1.f / BATCH);
        mean[f] = m;
        var[f] = sq * (1.f / BATCH) - m * m;
    }
}

// --------------------------------------------- batchnorm apply + hi/lo bf16 split
__global__ void bn_apply_split(const float* __restrict__ hr, const float* __restrict__ mean,
                               const float* __restrict__ var, const float* __restrict__ gamma,
                               const float* __restrict__ beta,
                               short* __restrict__ hi, short* __restrict__ lo) {
    int idx = blockIdx.x * 256 + threadIdx.x;   // 262144
    int f = idx & 255;
    float inv = rsqrtf(var[f] + BN_EPS);
    float v = (hr[idx] - mean[f]) * inv * gamma[f] + beta[f];
    short h = f2bf(v);
    hi[idx] = h;
    lo[idx] = f2bf(v - bf2f(h));
}

// ------------- out = sigmoid((hr_hi+hr_lo) @ Xb[:N_ENT]^T), m97-style LDS GEMM
// block 64(M) x 128(N), BK=32, 4 waves 2x2 (wave 32x64 = 2x4 frags, 16 MFMA/step)
// A LDS tile = [128][32] bf16: rows 0-63 = hr_hi, rows 64-127 = hr_lo
// B LDS tile = [128][32] bf16: 128 entity rows of Xb
// epilogue: sigmoid -> LDS fp32 [64][132] -> coalesced float4 NT stores
__global__ __launch_bounds__(256) void score_v2(const short* __restrict__ hrhi,
                                                const short* __restrict__ hrlo,
                                                const short* __restrict__ Xb,
                                                float* __restrict__ out) {
    __shared__ char smem[64 * 132 * 4];       // 33.8 KB (>= 16 KB A+B)
    short* As = (short*)smem;                 // [128][32]
    short* Bs = As + 4096;                    // [128][32]
    float* Ep = (float*)smem;                 // [64][132]

    const int tid  = threadIdx.x;
    const int wid  = tid >> 6;
    const int lane = tid & 63;
    const int wr = wid >> 1, wc = wid & 1;
    const int row0 = blockIdx.x * 64;         // M block (16)
    const int col0 = blockIdx.y * 128;        // N block (313)
    const int fr = lane & 15;
    const int kg = lane >> 4;
    const int lrow = lane >> 2;               // staging: row within 16-row chunk
    const int lchk = (lane & 3) * 8;          // staging: short offset within 64B row

    f32x4 acc[2][4] = {};

    for (int kb = 0; kb < 8; ++kb) {
        const int koff = kb * 32;
        // ---- stage A (2 chunks/wave) + B (2 chunks/wave) via global_load_lds
        {
            int c0 = wid * 2;
            #pragma unroll
            for (int c = 0; c < 2; ++c) {
                int ch = c0 + c;                       // 0..7
                int lr = ch * 16 + lrow;               // lds row 0..127
                const short* srcA = ((lr < 64) ? hrhi : hrlo)
                                  + (size_t)(row0 + (lr & 63)) * EMB + koff + lchk;
                gl_lds16(srcA, (char*)As + ch * 1024);
                int gc = col0 + lr;
                if (gc > N_ENT - 1) gc = N_ENT - 1;
                const short* srcB = Xb + (size_t)gc * EMB + koff + lchk;
                gl_lds16(srcB, (char*)Bs + ch * 1024);
            }
        }
        __syncthreads();
        // ---- fragments from LDS + MFMA
        short8 ahi[2], alo[2], b[4];
        #pragma unroll
        for (int i = 0; i < 2; ++i) {
            int r = wr * 32 + i * 16 + fr;
            ahi[i] = *(const short8*)&As[r * 32 + kg * 8];
            alo[i] = *(const short8*)&As[(64 + r) * 32 + kg * 8];
        }
        #pragma unroll
        for (int j = 0; j < 4; ++j) {
            int r = wc * 64 + j * 16 + fr;
            b[j] = *(const short8*)&Bs[r * 32 + kg * 8];
        }
        #pragma unroll
        for (int i = 0; i < 2; ++i)
            #pragma unroll
            for (int j = 0; j < 4; ++j) {
                acc[i][j] = __builtin_amdgcn_mfma_f32_16x16x32_bf16(ahi[i], b[j], acc[i][j], 0, 0, 0);
                acc[i][j] = __builtin_amdgcn_mfma_f32_16x16x32_bf16(alo[i], b[j], acc[i][j], 0, 0, 0);
            }
        __syncthreads();
    }

    // ---- epilogue: sigmoid -> LDS -> coalesced NT float4 stores
    #pragma unroll
    for (int i = 0; i < 2; ++i) {
        int rl = wr * 32 + i * 16 + (lane >> 4) * 4;
        #pragma unroll
        for (int j = 0; j < 4; ++j) {
            int cl = wc * 64 + j * 16 + (lane & 15);
            #pragma unroll
            for (int r = 0; r < 4; ++r)
                Ep[(rl + r) * 132 + cl] = 1.f / (1.f + __expf(-acc[i][j][r]));
        }
    }
    __syncthreads();
    #pragma unroll
    for (int it = 0; it < 8; ++it) {
        int idx = it * 256 + tid;
        int row = idx >> 5;
        int c4 = (idx & 31) << 2;
        f32x4 v = *(const f32x4*)&Ep[row * 132 + c4];
        int gc = col0 + c4;
        if (gc < N_ENT)
            __builtin_nontemporal_store(v, (f32x4*)(out + (size_t)(row0 + row) * N_ENT + gc));
    }
}

extern "C" void kernel_launch(void* const* d_in, const int* in_sizes, int n_in,
                              void* d_out, int out_size, void* d_ws, size_t ws_size,
                              hipStream_t stream) {
    const int*   e1    = (const int*)d_in[0];
    const int*   ri    = (const int*)d_in[1];
    const float* emb   = (const float*)d_in[3];
    const float* qw    = (const float*)d_in[4];
    const int*   esrc  = (const int*)d_in[5];
    const int*   edst  = (const int*)d_in[6];
    const float* evalv = (const float*)d_in[7];
    const float* gamma = (const float*)d_in[8];
    const float* beta  = (const float*)d_in[9];
    float* out = (float*)d_out;

    const size_t NODE_F = (size_t)N_NODES * EMB;   // 10,368,000
    short* support_bf = (short*)d_ws;              // NODE_F shorts (20.7 MB)
    float* X          = (float*)(support_bf + NODE_F);  // NODE_F floats
    short* Xb         = (short*)(X + NODE_F);      // NODE_F shorts
    float* hr         = (float*)(Xb + NODE_F);     // 262144
    float* mean       = hr + 262144;               // 256
    float* var        = mean + 256;                // 256
    int*   row_start  = (int*)(var + 256);         // N_NODES+1
    int*   cnt        = row_start + (N_NODES + 1); // N_NODES (cursor)
    int*   dst_s      = cnt + N_NODES;             // N_EDGES
    float* val_s      = (float*)(dst_s + N_EDGES); // N_EDGES
    short* hrhi       = (short*)(val_s + N_EDGES); // 262144 shorts
    short* hrlo       = hrhi + 262144;             // 262144 shorts
    short* Hthi       = hrlo + 262144;             // 65536 shorts
    short* Htlo       = Hthi + 65536;              // 65536 shorts
    // alias (lifetime-disjoint): ehi/elo live in X's storage; both are dead
    // before spmm_tanh writes X (support_mfma is their only consumer).
    short* ehi        = (short*)X;
    short* elo        = ehi + NODE_F;

    // CSR build (no fp atomics anywhere)
    hipMemsetAsync(cnt, 0, N_NODES * sizeof(int), stream);
    hist_k<<<(N_EDGES + 255) / 256, 256, 0, stream>>>(esrc, cnt);
    scan_k<<<1, 1024, 0, stream>>>(cnt, row_start);
    hipMemcpyAsync(cnt, row_start, N_NODES * sizeof(int), hipMemcpyDeviceToDevice, stream);

    build_hamilton_t<<<256, 256, 0, stream>>>(qw, Hthi, Htlo);
    cvt_emb<<<(int)(NODE_F / 1024), 256, 0, stream>>>(emb, ehi, elo);
    support_mfma<<<633, 256, 0, stream>>>(ehi, elo, Hthi, Htlo, support_bf);

    place_edges<<<(N_EDGES + 255) / 256, 256, 0, stream>>>(esrc, edst, evalv, cnt, dst_s, val_s);
    spmm_tanh<<<N_NODES / 4, 256, 0, stream>>>(row_start, dst_s, val_s, support_bf, X, Xb);

    hr_k<<<BATCH, 256, 0, stream>>>(X, e1, ri, hr);
    bn_stats<<<EMB, 256, 0, stream>>>(hr, mean, var);
    bn_apply_split<<<1024, 256, 0, stream>>>(hr, mean, var, gamma, beta, hrhi, hrlo);
    score_v2<<<dim3(16, 313), 256, 0, stream>>>(hrhi, hrlo, Xb, out);
}

// Round 9
// 335.107 us; speedup vs baseline: 7.7535x; 1.0425x over previous
//
#include <hip/hip_runtime.h>
#include <math.h>

#define N_ENT 40000
#define N_NODES 40500
#define EMB 256
#define N_EDGES 648000
#define BATCH 1024
#define BN_EPS 1e-5f

typedef __attribute__((ext_vector_type(8))) short short8;
typedef __attribute__((ext_vector_type(4))) float f32x4;
typedef __attribute__((ext_vector_type(4))) _Float16 half4v;

__device__ inline short f2bf(float f) {
    unsigned u = __float_as_uint(f);
    return (short)((u + 0x7FFFu + ((u >> 16) & 1u)) >> 16);
}
__device__ inline float bf2f(short s) {
    return __uint_as_float(((unsigned)(unsigned short)s) << 16);
}

__device__ __forceinline__ void gl_lds16(const void* g, void* l) {
    __builtin_amdgcn_global_load_lds(
        (const __attribute__((address_space(1))) void*)g,
        (__attribute__((address_space(3))) void*)l, 16, 0, 0);
}

// ------------------------------------------- hamilton, transposed, bf16 hi/lo
__global__ void build_hamilton_t(const float* __restrict__ qw,
                                 short* __restrict__ Hthi, short* __restrict__ Htlo) {
    int idx = blockIdx.x * 256 + threadIdx.x;   // 65536; idx = o*256 + i
    int o = idx >> 8, i = idx & 255;
    int p = i >> 6, i0 = i & 63;
    int q = o >> 6, o0 = o & 63;
    const int   ctab[16] = {0,1,2,3, 1,0,3,2, 2,3,0,1, 3,2,1,0};
    const float stab[16] = {1.f,1.f,1.f,1.f, -1.f,1.f,1.f,-1.f, -1.f,-1.f,1.f,1.f, -1.f,1.f,-1.f,1.f};
    float v = stab[p*4+q] * qw[i0*EMB + ctab[p*4+q]*64 + o0];
    short h = f2bf(v);
    Hthi[idx] = h;
    Htlo[idx] = f2bf(v - bf2f(h));
}

// --- support = emb @ H via 3-term hi/lo MFMA (~fp32 exact), emb converted
// --- in-register (no cvt_emb pass), output stored as fp16
__global__ __launch_bounds__(256) void support_mfma(const float* __restrict__ emb,
                                                    const short* __restrict__ Hthi,
                                                    const short* __restrict__ Htlo,
                                                    _Float16* __restrict__ Ch) {
    const int wid  = threadIdx.x >> 6;
    const int lane = threadIdx.x & 63;
    const int wr = wid >> 1, wc = wid & 1;
    const int row0 = blockIdx.x * 64 + wr * 32;
    const int col0 = wc * 128;
    const int fr = lane & 15;
    const int kg = lane >> 4;
    f32x4 acc[2][8] = {};
    for (int kb = 0; kb < 8; ++kb) {
        const int koff = kb * 32 + kg * 8;
        short8 ah[2], al[2];
        #pragma unroll
        for (int i = 0; i < 2; ++i) {
            int r = row0 + i * 16 + fr;
            if (r > N_NODES - 1) r = N_NODES - 1;
            const float* src = emb + (size_t)r * EMB + koff;
            float4 va = *(const float4*)(src);
            float4 vb = *(const float4*)(src + 4);
            float f[8] = {va.x, va.y, va.z, va.w, vb.x, vb.y, vb.z, vb.w};
            #pragma unroll
            for (int t = 0; t < 8; ++t) {
                short h = f2bf(f[t]);
                ah[i][t] = h;
                al[i][t] = f2bf(f[t] - bf2f(h));
            }
        }
        short8 bh[8], bl[8];
        #pragma unroll
        for (int j = 0; j < 8; ++j) {
            size_t off = (size_t)(col0 + j * 16 + fr) * EMB + koff;
            bh[j] = *(const short8*)(Hthi + off);
            bl[j] = *(const short8*)(Htlo + off);
        }
        #pragma unroll
        for (int i = 0; i < 2; ++i)
            #pragma unroll
            for (int j = 0; j < 8; ++j) {
                acc[i][j] = __builtin_amdgcn_mfma_f32_16x16x32_bf16(ah[i], bh[j], acc[i][j], 0, 0, 0);
                acc[i][j] = __builtin_amdgcn_mfma_f32_16x16x32_bf16(ah[i], bl[j], acc[i][j], 0, 0, 0);
                acc[i][j] = __builtin_amdgcn_mfma_f32_16x16x32_bf16(al[i], bh[j], acc[i][j], 0, 0, 0);
            }
    }
    #pragma unroll
    for (int i = 0; i < 2; ++i) {
        int rbase = row0 + i * 16 + (lane >> 4) * 4;
        #pragma unroll
        for (int j = 0; j < 8; ++j) {
            int c = col0 + j * 16 + (lane & 15);
            #pragma unroll
            for (int r = 0; r < 4; ++r) {
                if (rbase + r < N_NODES)
                    Ch[(size_t)(rbase + r) * EMB + c] = (_Float16)acc[i][j][r];
            }
        }
    }
}

// ---------------------------------------------------------------- CSR build
__global__ void hist_k(const int* __restrict__ src, int* __restrict__ cnt) {
    int e = blockIdx.x * 256 + threadIdx.x;
    if (e < N_EDGES) atomicAdd(&cnt[src[e]], 1);
}

__global__ __launch_bounds__(1024) void scan_k(const int* __restrict__ cnt,
                                               int* __restrict__ row_start) {
    __shared__ int wsum[16];
    __shared__ int carry_s;
    const int t = threadIdx.x;
    const int lane = t & 63, wid = t >> 6;
    if (t == 0) carry_s = 0;
    __syncthreads();
    for (int base = 0; base < N_NODES; base += 1024) {
        int idx = base + t;
        int v = (idx < N_NODES) ? cnt[idx] : 0;
        int incl = v;
        #pragma unroll
        for (int off = 1; off < 64; off <<= 1) {
            int u = __shfl_up(incl, off);
            if (lane >= off) incl += u;
        }
        if (lane == 63) wsum[wid] = incl;
        __syncthreads();
        if (t < 16) {
            int wv = wsum[t];
            #pragma unroll
            for (int off = 1; off < 16; off <<= 1) {
                int u = __shfl_up(wv, off);
                if (t >= off) wv += u;
            }
            wsum[t] = wv;
        }
        __syncthreads();
        int woff = (wid > 0) ? wsum[wid - 1] : 0;
        incl += woff;
        int c = carry_s;
        if (idx < N_NODES) row_start[idx] = c + incl - v;
        __syncthreads();
        if (t == 1023) carry_s = c + incl;
        __syncthreads();
    }
    if (t == 0) row_start[N_NODES] = carry_s;
}

__global__ void place_edges(const int* __restrict__ src, const int* __restrict__ dst,
                            const float* __restrict__ val, int* __restrict__ cursor,
                            int* __restrict__ dst_s, float* __restrict__ val_s) {
    int e = blockIdx.x * 256 + threadIdx.x;
    if (e >= N_EDGES) return;
    int pos = atomicAdd(&cursor[src[e]], 1);
    dst_s[pos] = dst[e];
    val_s[pos] = val[e];
}

// -------- X[row] = tanh( sum val*support_h[dst] ); fused fp32 X + bf16 Xb out
__global__ __launch_bounds__(256) void spmm_tanh(const int* __restrict__ row_start,
                                                 const int* __restrict__ dst_s,
                                                 const float* __restrict__ val_s,
                                                 const _Float16* __restrict__ support_h,
                                                 float* __restrict__ X,
                                                 short* __restrict__ Xb) {
    int row = blockIdx.x * 4 + (threadIdx.x >> 6);
    if (row >= N_NODES) return;
    int lane = threadIdx.x & 63;
    int beg = row_start[row], end = row_start[row + 1];
    float4 acc = make_float4(0.f, 0.f, 0.f, 0.f);
    for (int i = beg; i < end; ++i) {
        int d = dst_s[i];
        float v = val_s[i];
        half4v x = *(const half4v*)(support_h + (size_t)d * EMB + lane * 4);
        acc.x = fmaf(v, (float)x[0], acc.x);
        acc.y = fmaf(v, (float)x[1], acc.y);
        acc.z = fmaf(v, (float)x[2], acc.z);
        acc.w = fmaf(v, (float)x[3], acc.w);
    }
    float4 o;
    o.x = tanhf(acc.x); o.y = tanhf(acc.y); o.z = tanhf(acc.z); o.w = tanhf(acc.w);
    *(float4*)(X + (size_t)row * EMB + lane * 4) = o;
    short4 ob;
    ob.x = f2bf(o.x); ob.y = f2bf(o.y); ob.z = f2bf(o.z); ob.w = f2bf(o.w);
    *(short4*)(Xb + (size_t)row * EMB + lane * 4) = ob;
}

// ---------------------------------------------------------------- hr = X[e1] * X[r+N_ENT]
__global__ void hr_k(const float* __restrict__ X, const int* __restrict__ e1,
                     const int* __restrict__ ri, float* __restrict__ hr) {
    int b = blockIdx.x, f = threadIdx.x;
    float h = X[(size_t)e1[b] * EMB + f];
    float r = X[((size_t)ri[b] + N_ENT) * EMB + f];
    hr[b * EMB + f] = h * r;
}

// ---------------------------------------------------------------- batchnorm stats
__global__ __launch_bounds__(256) void bn_stats(const float* __restrict__ hr,
                                                float* __restrict__ mean,
                                                float* __restrict__ var) {
    int f = blockIdx.x, t = threadIdx.x;
    float s = 0.f, sq = 0.f;
    for (int b = t; b < BATCH; b += 256) {
        float v = hr[b * EMB + f];
        s += v; sq += v * v;
    }
    #pragma unroll
    for (int off = 32; off > 0; off >>= 1) {
        s  += __shfl_down(s, off);
        sq += __shfl_down(sq, off);
    }
    __shared__ float ss[4], sqs[4];
    int w = t >> 6;
    if ((t & 63) == 0) { ss[w] = s; sqs[w] = sq; }
    __syncthreads();
    if (t == 0) {
        s  = ss[0] + ss[1] + ss[2] + ss[3];
        sq = sqs[0] + sqs[1] + sqs[2] + sqs[3];
        float m = s * (1.f / BATCH);
        mean[f] = m;
        var[f] = sq * (1.f / BATCH) - m * m;
    }
}

// --------------------------------------------- batchnorm apply + hi/lo bf16 split
__global__ void bn_apply_split(const float* __restrict__ hr, const float* __restrict__ mean,
                               const float* __restrict__ var, const float* __restrict__ gamma,
                               const float* __restrict__ beta,
                               short* __restrict__ hi, short* __restrict__ lo) {
    int idx = blockIdx.x * 256 + threadIdx.x;   // 262144
    int f = idx & 255;
    float inv = rsqrtf(var[f] + BN_EPS);
    float v = (hr[idx] - mean[f]) * inv * gamma[f] + beta[f];
    short h = f2bf(v);
    hi[idx] = h;
    lo[idx] = f2bf(v - bf2f(h));
}

// ------------- out = sigmoid((hr_hi+hr_lo) @ Xb[:N_ENT]^T), m97-style LDS GEMM
// block 64(M) x 128(N), BK=32, 4 waves 2x2 (wave 32x64 = 2x4 frags, 16 MFMA/step)
__global__ __launch_bounds__(256) void score_v2(const short* __restrict__ hrhi,
                                                const short* __restrict__ hrlo,
                                                const short* __restrict__ Xb,
                                                float* __restrict__ out) {
    __shared__ char smem[64 * 132 * 4];       // 33.8 KB (>= 16 KB A+B)
    short* As = (short*)smem;                 // [128][32]
    short* Bs = As + 4096;                    // [128][32]
    float* Ep = (float*)smem;                 // [64][132]

    const int tid  = threadIdx.x;
    const int wid  = tid >> 6;
    const int lane = tid & 63;
    const int wr = wid >> 1, wc = wid & 1;
    const int row0 = blockIdx.x * 64;         // M block (16)
    const int col0 = blockIdx.y * 128;        // N block (313)
    const int fr = lane & 15;
    const int kg = lane >> 4;
    const int lrow = lane >> 2;               // staging: row within 16-row chunk
    const int lchk = (lane & 3) * 8;          // staging: short offset within 64B row

    f32x4 acc[2][4] = {};

    for (int kb = 0; kb < 8; ++kb) {
        const int koff = kb * 32;
        {
            int c0 = wid * 2;
            #pragma unroll
            for (int c = 0; c < 2; ++c) {
                int ch = c0 + c;                       // 0..7
                int lr = ch * 16 + lrow;               // lds row 0..127
                const short* srcA = ((lr < 64) ? hrhi : hrlo)
                                  + (size_t)(row0 + (lr & 63)) * EMB + koff + lchk;
                gl_lds16(srcA, (char*)As + ch * 1024);
                int gc = col0 + lr;
                if (gc > N_ENT - 1) gc = N_ENT - 1;
                const short* srcB = Xb + (size_t)gc * EMB + koff + lchk;
                gl_lds16(srcB, (char*)Bs + ch * 1024);
            }
        }
        __syncthreads();
        short8 ahi[2], alo[2], b[4];
        #pragma unroll
        for (int i = 0; i < 2; ++i) {
            int r = wr * 32 + i * 16 + fr;
            ahi[i] = *(const short8*)&As[r * 32 + kg * 8];
            alo[i] = *(const short8*)&As[(64 + r) * 32 + kg * 8];
        }
        #pragma unroll
        for (int j = 0; j < 4; ++j) {
            int r = wc * 64 + j * 16 + fr;
            b[j] = *(const short8*)&Bs[r * 32 + kg * 8];
        }
        #pragma unroll
        for (int i = 0; i < 2; ++i)
            #pragma unroll
            for (int j = 0; j < 4; ++j) {
                acc[i][j] = __builtin_amdgcn_mfma_f32_16x16x32_bf16(ahi[i], b[j], acc[i][j], 0, 0, 0);
                acc[i][j] = __builtin_amdgcn_mfma_f32_16x16x32_bf16(alo[i], b[j], acc[i][j], 0, 0, 0);
            }
        __syncthreads();
    }

    // ---- epilogue: sigmoid -> LDS -> coalesced NT float4 stores
    #pragma unroll
    for (int i = 0; i < 2; ++i) {
        int rl = wr * 32 + i * 16 + (lane >> 4) * 4;
        #pragma unroll
        for (int j = 0; j < 4; ++j) {
            int cl = wc * 64 + j * 16 + (lane & 15);
            #pragma unroll
            for (int r = 0; r < 4; ++r)
                Ep[(rl + r) * 132 + cl] = 1.f / (1.f + __expf(-acc[i][j][r]));
        }
    }
    __syncthreads();
    #pragma unroll
    for (int it = 0; it < 8; ++it) {
        int idx = it * 256 + tid;
        int row = idx >> 5;
        int c4 = (idx & 31) << 2;
        f32x4 v = *(const f32x4*)&Ep[row * 132 + c4];
        int gc = col0 + c4;
        if (gc < N_ENT)
            __builtin_nontemporal_store(v, (f32x4*)(out + (size_t)(row0 + row) * N_ENT + gc));
    }
}

extern "C" void kernel_launch(void* const* d_in, const int* in_sizes, int n_in,
                              void* d_out, int out_size, void* d_ws, size_t ws_size,
                              hipStream_t stream) {
    const int*   e1    = (const int*)d_in[0];
    const int*   ri    = (const int*)d_in[1];
    const float* emb   = (const float*)d_in[3];
    const float* qw    = (const float*)d_in[4];
    const int*   esrc  = (const int*)d_in[5];
    const int*   edst  = (const int*)d_in[6];
    const float* evalv = (const float*)d_in[7];
    const float* gamma = (const float*)d_in[8];
    const float* beta  = (const float*)d_in[9];
    float* out = (float*)d_out;

    const size_t NODE_F = (size_t)N_NODES * EMB;   // 10,368,000
    _Float16* support_h = (_Float16*)d_ws;         // NODE_F halfs (20.7 MB)
    float* X          = (float*)(support_h + NODE_F);   // NODE_F floats
    short* Xb         = (short*)(X + NODE_F);      // NODE_F shorts
    float* hr         = (float*)(Xb + NODE_F);     // 262144
    float* mean       = hr + 262144;               // 256
    float* var        = mean + 256;                // 256
    int*   row_start  = (int*)(var + 256);         // N_NODES+1
    int*   cnt        = row_start + (N_NODES + 1); // N_NODES (cursor)
    int*   dst_s      = cnt + N_NODES;             // N_EDGES
    float* val_s      = (float*)(dst_s + N_EDGES); // N_EDGES
    short* hrhi       = (short*)(val_s + N_EDGES); // 262144 shorts
    short* hrlo       = hrhi + 262144;             // 262144 shorts
    short* Hthi       = hrlo + 262144;             // 65536 shorts
    short* Htlo       = Hthi + 65536;              // 65536 shorts

    // CSR build (no fp atomics anywhere)
    hipMemsetAsync(cnt, 0, N_NODES * sizeof(int), stream);
    hist_k<<<(N_EDGES + 255) / 256, 256, 0, stream>>>(esrc, cnt);
    scan_k<<<1, 1024, 0, stream>>>(cnt, row_start);
    hipMemcpyAsync(cnt, row_start, N_NODES * sizeof(int), hipMemcpyDeviceToDevice, stream);

    build_hamilton_t<<<256, 256, 0, stream>>>(qw, Hthi, Htlo);
    support_mfma<<<633, 256, 0, stream>>>(emb, Hthi, Htlo, support_h);

    place_edges<<<(N_EDGES + 255) / 256, 256, 0, stream>>>(esrc, edst, evalv, cnt, dst_s, val_s);
    spmm_tanh<<<N_NODES / 4, 256, 0, stream>>>(row_start, dst_s, val_s, support_h, X, Xb);

    hr_k<<<BATCH, 256, 0, stream>>>(X, e1, ri, hr);
    bn_stats<<<EMB, 256, 0, stream>>>(hr, mean, var);
    bn_apply_split<<<1024, 256, 0, stream>>>(hr, mean, var, gamma, beta, hrhi, hrlo);
    score_v2<<<dim3(16, 313), 256, 0, stream>>>(hrhi, hrlo, Xb, out);
}

// Round 10
// 279.009 us; speedup vs baseline: 9.3124x; 1.2011x over previous
//
#include <hip/hip_runtime.h>
#include <math.h>

#define N_ENT 40000
#define N_NODES 40500
#define EMB 256
#define N_EDGES 648000
#define BATCH 1024
#define BN_EPS 1e-5f
#define SCAN_NB 40   // ceil(N_NODES/1024)

typedef __attribute__((ext_vector_type(8))) _Float16 half8;
typedef __attribute__((ext_vector_type(4))) _Float16 half4v;
typedef __attribute__((ext_vector_type(4))) float f32x4;

__device__ __forceinline__ void gl_lds16(const void* g, void* l) {
    __builtin_amdgcn_global_load_lds(
        (const __attribute__((address_space(1))) void*)g,
        (__attribute__((address_space(3))) void*)l, 16, 0, 0);
}

// ------------------------------------------- hamilton, transposed, fp16
__global__ void build_hamilton_h(const float* __restrict__ qw,
                                 _Float16* __restrict__ Hth) {
    int idx = blockIdx.x * 256 + threadIdx.x;   // 65536; idx = o*256 + i
    int o = idx >> 8, i = idx & 255;
    int p = i >> 6, i0 = i & 63;
    int q = o >> 6, o0 = o & 63;
    const int   ctab[16] = {0,1,2,3, 1,0,3,2, 2,3,0,1, 3,2,1,0};
    const float stab[16] = {1.f,1.f,1.f,1.f, -1.f,1.f,1.f,-1.f, -1.f,-1.f,1.f,1.f, -1.f,1.f,-1.f,1.f};
    float v = stab[p*4+q] * qw[i0*EMB + ctab[p*4+q]*64 + o0];
    Hth[idx] = (_Float16)v;
}

// --- support = emb @ H, single fp16 MFMA (support stored fp16 — matching precision)
__global__ __launch_bounds__(256) void support_mfma(const float* __restrict__ emb,
                                                    const _Float16* __restrict__ Hth,
                                                    _Float16* __restrict__ Ch) {
    const int wid  = threadIdx.x >> 6;
    const int lane = threadIdx.x & 63;
    const int wr = wid >> 1, wc = wid & 1;
    const int row0 = blockIdx.x * 64 + wr * 32;
    const int col0 = wc * 128;
    const int fr = lane & 15;
    const int kg = lane >> 4;
    f32x4 acc[2][8] = {};
    for (int kb = 0; kb < 8; ++kb) {
        const int koff = kb * 32 + kg * 8;
        half8 a[2];
        #pragma unroll
        for (int i = 0; i < 2; ++i) {
            int r = row0 + i * 16 + fr;
            if (r > N_NODES - 1) r = N_NODES - 1;
            const float* src = emb + (size_t)r * EMB + koff;
            float4 va = *(const float4*)(src);
            float4 vb = *(const float4*)(src + 4);
            a[i][0] = (_Float16)va.x; a[i][1] = (_Float16)va.y;
            a[i][2] = (_Float16)va.z; a[i][3] = (_Float16)va.w;
            a[i][4] = (_Float16)vb.x; a[i][5] = (_Float16)vb.y;
            a[i][6] = (_Float16)vb.z; a[i][7] = (_Float16)vb.w;
        }
        half8 b[8];
        #pragma unroll
        for (int j = 0; j < 8; ++j)
            b[j] = *(const half8*)(Hth + (size_t)(col0 + j * 16 + fr) * EMB + koff);
        #pragma unroll
        for (int i = 0; i < 2; ++i)
            #pragma unroll
            for (int j = 0; j < 8; ++j)
                acc[i][j] = __builtin_amdgcn_mfma_f32_16x16x32_f16(a[i], b[j], acc[i][j], 0, 0, 0);
    }
    #pragma unroll
    for (int i = 0; i < 2; ++i) {
        int rbase = row0 + i * 16 + (lane >> 4) * 4;
        #pragma unroll
        for (int j = 0; j < 8; ++j) {
            int c = col0 + j * 16 + (lane & 15);
            #pragma unroll
            for (int r = 0; r < 4; ++r) {
                if (rbase + r < N_NODES)
                    Ch[(size_t)(rbase + r) * EMB + c] = (_Float16)acc[i][j][r];
            }
        }
    }
}

// ---------------------------------------------------------------- CSR build
__global__ void hist_k(const int* __restrict__ src, int* __restrict__ cnt) {
    int e = blockIdx.x * 256 + threadIdx.x;
    if (e < N_EDGES) atomicAdd(&cnt[src[e]], 1);
}

// per-block (1024) exclusive scan -> row_start (block-local) + block sums
__global__ __launch_bounds__(1024) void scan_blocks(const int* __restrict__ cnt,
                                                    int* __restrict__ row_start,
                                                    int* __restrict__ bsum) {
    __shared__ int wsum[16];
    const int t = threadIdx.x;
    const int lane = t & 63, wid = t >> 6;
    int idx = blockIdx.x * 1024 + t;
    int v = (idx < N_NODES) ? cnt[idx] : 0;
    int incl = v;
    #pragma unroll
    for (int off = 1; off < 64; off <<= 1) {
        int u = __shfl_up(incl, off);
        if (lane >= off) incl += u;
    }
    if (lane == 63) wsum[wid] = incl;
    __syncthreads();
    if (t < 16) {
        int wv = wsum[t];
        #pragma unroll
        for (int off = 1; off < 16; off <<= 1) {
            int u = __shfl_up(wv, off);
            if (t >= off) wv += u;
        }
        wsum[t] = wv;
    }
    __syncthreads();
    int woff = (wid > 0) ? wsum[wid - 1] : 0;
    incl += woff;
    if (idx < N_NODES) row_start[idx] = incl - v;   // block-local exclusive
    if (t == 1023) bsum[blockIdx.x] = incl;
}

// single-wave exclusive scan of the 40 block sums (in place); bsum[NB] = total
__global__ void scan_tops(int* __restrict__ bsum) {
    int t = threadIdx.x;                 // 64 threads
    int v = (t < SCAN_NB) ? bsum[t] : 0;
    int incl = v;
    #pragma unroll
    for (int off = 1; off < 64; off <<= 1) {
        int u = __shfl_up(incl, off);
        if (t >= off) incl += u;
    }
    if (t < SCAN_NB) bsum[t] = incl - v;
    if (t == SCAN_NB - 1) bsum[SCAN_NB] = incl;
}

// add block offsets; also fill cursor copy and the tail element
__global__ __launch_bounds__(1024) void scan_add(int* __restrict__ row_start,
                                                 int* __restrict__ cursor,
                                                 const int* __restrict__ bsum) {
    int idx = blockIdx.x * 1024 + threadIdx.x;
    if (idx < N_NODES) {
        int v = row_start[idx] + bsum[blockIdx.x];
        row_start[idx] = v;
        cursor[idx] = v;
    }
    if (idx == N_NODES) row_start[N_NODES] = bsum[SCAN_NB];
}

__global__ void place_edges(const int* __restrict__ src, const int* __restrict__ dst,
                            const float* __restrict__ val, int* __restrict__ cursor,
                            int* __restrict__ dst_s, float* __restrict__ val_s) {
    int e = blockIdx.x * 256 + threadIdx.x;
    if (e >= N_EDGES) return;
    int pos = atomicAdd(&cursor[src[e]], 1);
    dst_s[pos] = dst[e];
    val_s[pos] = val[e];
}

// -------- Xh[row] = tanh( sum val*support_h[dst] )  (fp16 out only)
__global__ __launch_bounds__(256) void spmm_tanh(const int* __restrict__ row_start,
                                                 const int* __restrict__ dst_s,
                                                 const float* __restrict__ val_s,
                                                 const _Float16* __restrict__ support_h,
                                                 _Float16* __restrict__ Xh) {
    int row = blockIdx.x * 4 + (threadIdx.x >> 6);
    if (row >= N_NODES) return;
    int lane = threadIdx.x & 63;
    int beg = row_start[row], end = row_start[row + 1];
    float4 acc = make_float4(0.f, 0.f, 0.f, 0.f);
    for (int i = beg; i < end; ++i) {
        int d = dst_s[i];
        float v = val_s[i];
        half4v x = *(const half4v*)(support_h + (size_t)d * EMB + lane * 4);
        acc.x = fmaf(v, (float)x[0], acc.x);
        acc.y = fmaf(v, (float)x[1], acc.y);
        acc.z = fmaf(v, (float)x[2], acc.z);
        acc.w = fmaf(v, (float)x[3], acc.w);
    }
    half4v o;
    o[0] = (_Float16)tanhf(acc.x); o[1] = (_Float16)tanhf(acc.y);
    o[2] = (_Float16)tanhf(acc.z); o[3] = (_Float16)tanhf(acc.w);
    *(half4v*)(Xh + (size_t)row * EMB + lane * 4) = o;
}

// ---------------------------------------------------------------- hr = X[e1]*X[r+N_ENT]
__global__ void hr_k(const _Float16* __restrict__ Xh, const int* __restrict__ e1,
                     const int* __restrict__ ri, float* __restrict__ hr) {
    int b = blockIdx.x, f = threadIdx.x;
    float h = (float)Xh[(size_t)e1[b] * EMB + f];
    float r = (float)Xh[((size_t)ri[b] + N_ENT) * EMB + f];
    hr[b * EMB + f] = h * r;
}

// ---------------------------------------------------------------- batchnorm stats
__global__ __launch_bounds__(256) void bn_stats(const float* __restrict__ hr,
                                                float* __restrict__ mean,
                                                float* __restrict__ var) {
    int f = blockIdx.x, t = threadIdx.x;
    float s = 0.f, sq = 0.f;
    for (int b = t; b < BATCH; b += 256) {
        float v = hr[b * EMB + f];
        s += v; sq += v * v;
    }
    #pragma unroll
    for (int off = 32; off > 0; off >>= 1) {
        s  += __shfl_down(s, off);
        sq += __shfl_down(sq, off);
    }
    __shared__ float ss[4], sqs[4];
    int w = t >> 6;
    if ((t & 63) == 0) { ss[w] = s; sqs[w] = sq; }
    __syncthreads();
    if (t == 0) {
        s  = ss[0] + ss[1] + ss[2] + ss[3];
        sq = sqs[0] + sqs[1] + sqs[2] + sqs[3];
        float m = s * (1.f / BATCH);
        mean[f] = m;
        var[f] = sq * (1.f / BATCH) - m * m;
    }
}

// --------------------------------------------- batchnorm apply -> fp16
__global__ void bn_apply_h(const float* __restrict__ hr, const float* __restrict__ mean,
                           const float* __restrict__ var, const float* __restrict__ gamma,
                           const float* __restrict__ beta, _Float16* __restrict__ hr_h) {
    int idx = blockIdx.x * 256 + threadIdx.x;   // 262144
    int f = idx & 255;
    float inv = rsqrtf(var[f] + BN_EPS);
    float v = (hr[idx] - mean[f]) * inv * gamma[f] + beta[f];
    hr_h[idx] = (_Float16)v;
}

// ------------- out = sigmoid(hr_h @ Xh[:N_ENT]^T), fp16 MFMA LDS GEMM
// block 64(M) x 128(N), BK=32, 4 waves 2x2 (wave 32x64 = 2x4 frags, 8 MFMA/step)
// A LDS [64][32] fp16 (4 chunks), B LDS [128][32] fp16 (8 chunks); 3 chunks/wave
__global__ __launch_bounds__(256) void score_v3(const _Float16* __restrict__ hr_h,
                                                const _Float16* __restrict__ Xh,
                                                float* __restrict__ out) {
    __shared__ char smem[64 * 132 * 4];       // 33.8 KB (>= 12 KB A+B)
    _Float16* As = (_Float16*)smem;           // [64][32]
    _Float16* Bs = As + 2048;                 // [128][32]
    float* Ep = (float*)smem;                 // [64][132]

    const int tid  = threadIdx.x;
    const int wid  = tid >> 6;
    const int lane = tid & 63;
    const int wr = wid >> 1, wc = wid & 1;
    const int row0 = blockIdx.x * 64;         // M block (16)
    const int col0 = blockIdx.y * 128;        // N block (313)
    const int fr = lane & 15;
    const int kg = lane >> 4;
    const int lrow = lane >> 2;               // staging: row within 16-row chunk
    const int lchk = (lane & 3) * 8;          // staging: half offset within 64B row

    f32x4 acc[2][4] = {};

    for (int kb = 0; kb < 8; ++kb) {
        const int koff = kb * 32;
        // ---- stage A (chunks 0-3) + B (chunks 4-11); 3 chunks per wave
        #pragma unroll
        for (int c = 0; c < 3; ++c) {
            int ch = wid * 3 + c;                      // 0..11
            if (ch < 4) {
                int lr = ch * 16 + lrow;               // 0..63
                const _Float16* srcA = hr_h + (size_t)(row0 + lr) * EMB + koff + lchk;
                gl_lds16(srcA, smem + ch * 1024);
            } else {
                int br = (ch - 4) * 16 + lrow;         // 0..127
                int gc = col0 + br;
                if (gc > N_ENT - 1) gc = N_ENT - 1;
                const _Float16* srcB = Xh + (size_t)gc * EMB + koff + lchk;
                gl_lds16(srcB, smem + ch * 1024);
            }
        }
        __syncthreads();
        // ---- fragments from LDS + MFMA
        half8 a_[2], b_[4];
        #pragma unroll
        for (int i = 0; i < 2; ++i) {
            int r = wr * 32 + i * 16 + fr;
            a_[i] = *(const half8*)&As[r * 32 + kg * 8];
        }
        #pragma unroll
        for (int j = 0; j < 4; ++j) {
            int r = wc * 64 + j * 16 + fr;
            b_[j] = *(const half8*)&Bs[r * 32 + kg * 8];
        }
        #pragma unroll
        for (int i = 0; i < 2; ++i)
            #pragma unroll
            for (int j = 0; j < 4; ++j)
                acc[i][j] = __builtin_amdgcn_mfma_f32_16x16x32_f16(a_[i], b_[j], acc[i][j], 0, 0, 0);
        __syncthreads();
    }

    // ---- epilogue: sigmoid -> LDS -> coalesced NT float4 stores
    #pragma unroll
    for (int i = 0; i < 2; ++i) {
        int rl = wr * 32 + i * 16 + (lane >> 4) * 4;
        #pragma unroll
        for (int j = 0; j < 4; ++j) {
            int cl = wc * 64 + j * 16 + (lane & 15);
            #pragma unroll
            for (int r = 0; r < 4; ++r)
                Ep[(rl + r) * 132 + cl] = 1.f / (1.f + __expf(-acc[i][j][r]));
        }
    }
    __syncthreads();
    #pragma unroll
    for (int it = 0; it < 8; ++it) {
        int idx = it * 256 + tid;
        int row = idx >> 5;
        int c4 = (idx & 31) << 2;
        f32x4 v = *(const f32x4*)&Ep[row * 132 + c4];
        int gc = col0 + c4;
        if (gc < N_ENT)
            __builtin_nontemporal_store(v, (f32x4*)(out + (size_t)(row0 + row) * N_ENT + gc));
    }
}

extern "C" void kernel_launch(void* const* d_in, const int* in_sizes, int n_in,
                              void* d_out, int out_size, void* d_ws, size_t ws_size,
                              hipStream_t stream) {
    const int*   e1    = (const int*)d_in[0];
    const int*   ri    = (const int*)d_in[1];
    const float* emb   = (const float*)d_in[3];
    const float* qw    = (const float*)d_in[4];
    const int*   esrc  = (const int*)d_in[5];
    const int*   edst  = (const int*)d_in[6];
    const float* evalv = (const float*)d_in[7];
    const float* gamma = (const float*)d_in[8];
    const float* beta  = (const float*)d_in[9];
    float* out = (float*)d_out;

    const size_t NODE_F = (size_t)N_NODES * EMB;        // 10,368,000
    _Float16* support_h = (_Float16*)d_ws;              // NODE_F halfs
    _Float16* Xh        = support_h + NODE_F;           // NODE_F halfs
    float*    hr        = (float*)(Xh + NODE_F);        // 262144
    float*    mean      = hr + 262144;                  // 256
    float*    var       = mean + 256;                   // 256
    int*      row_start = (int*)(var + 256);            // N_NODES+1
    int*      cnt       = row_start + (N_NODES + 1);    // N_NODES
    int*      cursor    = cnt + N_NODES;                // N_NODES
    int*      bsum      = cursor + N_NODES;             // SCAN_NB+1
    int*      dst_s     = bsum + SCAN_NB + 1;           // N_EDGES
    float*    val_s     = (float*)(dst_s + N_EDGES);    // N_EDGES
    _Float16* hr_h      = (_Float16*)(val_s + N_EDGES); // 262144 halfs
    _Float16* Hth       = hr_h + 262144;                // 65536 halfs

    // CSR build (no fp atomics; parallel scan)
    hipMemsetAsync(cnt, 0, N_NODES * sizeof(int), stream);
    hist_k<<<(N_EDGES + 255) / 256, 256, 0, stream>>>(esrc, cnt);
    scan_blocks<<<SCAN_NB, 1024, 0, stream>>>(cnt, row_start, bsum);
    scan_tops<<<1, 64, 0, stream>>>(bsum);
    scan_add<<<SCAN_NB, 1024, 0, stream>>>(row_start, cursor, bsum);

    build_hamilton_h<<<256, 256, 0, stream>>>(qw, Hth);
    support_mfma<<<633, 256, 0, stream>>>(emb, Hth, support_h);

    place_edges<<<(N_EDGES + 255) / 256, 256, 0, stream>>>(esrc, edst, evalv, cursor, dst_s, val_s);
    spmm_tanh<<<N_NODES / 4, 256, 0, stream>>>(row_start, dst_s, val_s, support_h, Xh);

    hr_k<<<BATCH, 256, 0, stream>>>(Xh, e1, ri, hr);
    bn_stats<<<EMB, 256, 0, stream>>>(hr, mean, var);
    bn_apply_h<<<1024, 256, 0, stream>>>(hr, mean, var, gamma, beta, hr_h);
    score_v3<<<dim3(16, 313), 256, 0, stream>>>(hr_h, Xh, out);
}

// Round 11
// 226.020 us; speedup vs baseline: 11.4957x; 1.2344x over previous
//
#include <hip/hip_runtime.h>
#include <math.h>

#define N_ENT 40000
#define N_NODES 40500
#define EMB 256
#define N_EDGES 648000
#define BATCH 1024
#define BN_EPS 1e-5f
#define SCAN_NB 40   // ceil(N_NODES/1024)

typedef __attribute__((ext_vector_type(8))) _Float16 half8;
typedef __attribute__((ext_vector_type(4))) _Float16 half4v;
typedef __attribute__((ext_vector_type(4))) float f32x4;

__device__ __forceinline__ void gl_lds16(const void* g, void* l) {
    __builtin_amdgcn_global_load_lds(
        (const __attribute__((address_space(1))) void*)g,
        (__attribute__((address_space(3))) void*)l, 16, 0, 0);
}

// ---------------------------------------------------------------- CSR: histogram
__global__ void hist_k(const int* __restrict__ src, int* __restrict__ cnt) {
    int e = blockIdx.x * 256 + threadIdx.x;
    if (e < N_EDGES) atomicAdd(&cnt[src[e]], 1);
}

// ---- fused: blocks 0..39 = per-block scan of cnt; blocks 40..103 = hamilton fp16
__global__ __launch_bounds__(1024) void scanham(const int* __restrict__ cnt,
                                                int* __restrict__ row_start,
                                                int* __restrict__ bsum,
                                                const float* __restrict__ qw,
                                                _Float16* __restrict__ Hth) {
    const int t = threadIdx.x;
    if (blockIdx.x < SCAN_NB) {
        __shared__ int wsum[16];
        const int lane = t & 63, wid = t >> 6;
        int idx = blockIdx.x * 1024 + t;
        int v = (idx < N_NODES) ? cnt[idx] : 0;
        int incl = v;
        #pragma unroll
        for (int off = 1; off < 64; off <<= 1) {
            int u = __shfl_up(incl, off);
            if (lane >= off) incl += u;
        }
        if (lane == 63) wsum[wid] = incl;
        __syncthreads();
        if (t < 16) {
            int wv = wsum[t];
            #pragma unroll
            for (int off = 1; off < 16; off <<= 1) {
                int u = __shfl_up(wv, off);
                if (t >= off) wv += u;
            }
            wsum[t] = wv;
        }
        __syncthreads();
        int woff = (wid > 0) ? wsum[wid - 1] : 0;
        incl += woff;
        if (idx < N_NODES) row_start[idx] = incl - v;   // block-local exclusive
        if (t == 1023) bsum[blockIdx.x] = incl;
    } else {
        int idx = (blockIdx.x - SCAN_NB) * 1024 + t;    // 65536
        int o = idx >> 8, i = idx & 255;
        int p = i >> 6, i0 = i & 63;
        int q = o >> 6, o0 = o & 63;
        const int   ctab[16] = {0,1,2,3, 1,0,3,2, 2,3,0,1, 3,2,1,0};
        const float stab[16] = {1.f,1.f,1.f,1.f, -1.f,1.f,1.f,-1.f, -1.f,-1.f,1.f,1.f, -1.f,1.f,-1.f,1.f};
        Hth[idx] = (_Float16)(stab[p*4+q] * qw[i0*EMB + ctab[p*4+q]*64 + o0]);
    }
}

// ---- scan_add: each block redoes the 40-element top scan, adds offset,
// ---- writes row_start + cursor (+ total tail)
__global__ __launch_bounds__(1024) void scan_add(int* __restrict__ row_start,
                                                 int* __restrict__ cursor,
                                                 const int* __restrict__ bsum) {
    __shared__ int off_s, tot_s;
    const int t = threadIdx.x;
    if (t < 64) {
        int v = (t < SCAN_NB) ? bsum[t] : 0;
        int incl = v;
        #pragma unroll
        for (int off = 1; off < 64; off <<= 1) {
            int u = __shfl_up(incl, off);
            if (t >= off) incl += u;
        }
        int off = (blockIdx.x == 0) ? 0 : __shfl(incl, (int)blockIdx.x - 1);
        int tot = __shfl(incl, SCAN_NB - 1);
        if (t == 0) { off_s = off; tot_s = tot; }
    }
    __syncthreads();
    int idx = blockIdx.x * 1024 + t;
    if (idx < N_NODES) {
        int v = row_start[idx] + off_s;
        row_start[idx] = v;
        cursor[idx] = v;
    }
    if (idx == N_NODES) row_start[N_NODES] = tot_s;
}

// ---- fused: blocks 0..632 = support GEMM (fp16 MFMA); blocks 633.. = place_edges
__global__ __launch_bounds__(256) void support_place(const float* __restrict__ emb,
                                                     const _Float16* __restrict__ Hth,
                                                     _Float16* __restrict__ Ch,
                                                     const int* __restrict__ esrc,
                                                     const int* __restrict__ edst,
                                                     const float* __restrict__ evalv,
                                                     int* __restrict__ cursor,
                                                     int2* __restrict__ edge_s) {
    if (blockIdx.x >= 633) {
        int e = (blockIdx.x - 633) * 256 + threadIdx.x;
        if (e < N_EDGES) {
            int pos = atomicAdd(&cursor[esrc[e]], 1);
            edge_s[pos] = make_int2(edst[e], __float_as_int(evalv[e]));
        }
        return;
    }
    const int wid  = threadIdx.x >> 6;
    const int lane = threadIdx.x & 63;
    const int wr = wid >> 1, wc = wid & 1;
    const int row0 = blockIdx.x * 64 + wr * 32;
    const int col0 = wc * 128;
    const int fr = lane & 15;
    const int kg = lane >> 4;
    f32x4 acc[2][8] = {};
    for (int kb = 0; kb < 8; ++kb) {
        const int koff = kb * 32 + kg * 8;
        half8 a[2];
        #pragma unroll
        for (int i = 0; i < 2; ++i) {
            int r = row0 + i * 16 + fr;
            if (r > N_NODES - 1) r = N_NODES - 1;
            const float* src = emb + (size_t)r * EMB + koff;
            float4 va = *(const float4*)(src);
            float4 vb = *(const float4*)(src + 4);
            a[i][0] = (_Float16)va.x; a[i][1] = (_Float16)va.y;
            a[i][2] = (_Float16)va.z; a[i][3] = (_Float16)va.w;
            a[i][4] = (_Float16)vb.x; a[i][5] = (_Float16)vb.y;
            a[i][6] = (_Float16)vb.z; a[i][7] = (_Float16)vb.w;
        }
        half8 b[8];
        #pragma unroll
        for (int j = 0; j < 8; ++j)
            b[j] = *(const half8*)(Hth + (size_t)(col0 + j * 16 + fr) * EMB + koff);
        #pragma unroll
        for (int i = 0; i < 2; ++i)
            #pragma unroll
            for (int j = 0; j < 8; ++j)
                acc[i][j] = __builtin_amdgcn_mfma_f32_16x16x32_f16(a[i], b[j], acc[i][j], 0, 0, 0);
    }
    #pragma unroll
    for (int i = 0; i < 2; ++i) {
        int rbase = row0 + i * 16 + (lane >> 4) * 4;
        #pragma unroll
        for (int j = 0; j < 8; ++j) {
            int c = col0 + j * 16 + (lane & 15);
            #pragma unroll
            for (int r = 0; r < 4; ++r) {
                if (rbase + r < N_NODES)
                    Ch[(size_t)(rbase + r) * EMB + c] = (_Float16)acc[i][j][r];
            }
        }
    }
}

// -------- Xh[row] = tanh( sum val*support_h[dst] ), int2 edges, 4-wide unroll
__global__ __launch_bounds__(256) void spmm_tanh(const int* __restrict__ row_start,
                                                 const int2* __restrict__ edge_s,
                                                 const _Float16* __restrict__ support_h,
                                                 _Float16* __restrict__ Xh) {
    int row = blockIdx.x * 4 + (threadIdx.x >> 6);
    if (row >= N_NODES) return;
    int lane = threadIdx.x & 63;
    int beg = row_start[row], end = row_start[row + 1];
    float4 acc = make_float4(0.f, 0.f, 0.f, 0.f);
    int i = beg;
    for (; i + 3 < end; i += 4) {
        int2 e0 = edge_s[i], e1 = edge_s[i+1], e2 = edge_s[i+2], e3 = edge_s[i+3];
        half4v x0 = *(const half4v*)(support_h + (size_t)e0.x * EMB + lane * 4);
        half4v x1 = *(const half4v*)(support_h + (size_t)e1.x * EMB + lane * 4);
        half4v x2 = *(const half4v*)(support_h + (size_t)e2.x * EMB + lane * 4);
        half4v x3 = *(const half4v*)(support_h + (size_t)e3.x * EMB + lane * 4);
        float v0 = __int_as_float(e0.y), v1 = __int_as_float(e1.y);
        float v2 = __int_as_float(e2.y), v3 = __int_as_float(e3.y);
        acc.x = fmaf(v0, (float)x0[0], acc.x); acc.y = fmaf(v0, (float)x0[1], acc.y);
        acc.z = fmaf(v0, (float)x0[2], acc.z); acc.w = fmaf(v0, (float)x0[3], acc.w);
        acc.x = fmaf(v1, (float)x1[0], acc.x); acc.y = fmaf(v1, (float)x1[1], acc.y);
        acc.z = fmaf(v1, (float)x1[2], acc.z); acc.w = fmaf(v1, (float)x1[3], acc.w);
        acc.x = fmaf(v2, (float)x2[0], acc.x); acc.y = fmaf(v2, (float)x2[1], acc.y);
        acc.z = fmaf(v2, (float)x2[2], acc.z); acc.w = fmaf(v2, (float)x2[3], acc.w);
        acc.x = fmaf(v3, (float)x3[0], acc.x); acc.y = fmaf(v3, (float)x3[1], acc.y);
        acc.z = fmaf(v3, (float)x3[2], acc.z); acc.w = fmaf(v3, (float)x3[3], acc.w);
    }
    for (; i < end; ++i) {
        int2 e = edge_s[i];
        float v = __int_as_float(e.y);
        half4v x = *(const half4v*)(support_h + (size_t)e.x * EMB + lane * 4);
        acc.x = fmaf(v, (float)x[0], acc.x);
        acc.y = fmaf(v, (float)x[1], acc.y);
        acc.z = fmaf(v, (float)x[2], acc.z);
        acc.w = fmaf(v, (float)x[3], acc.w);
    }
    half4v o;
    o[0] = (_Float16)tanhf(acc.x); o[1] = (_Float16)tanhf(acc.y);
    o[2] = (_Float16)tanhf(acc.z); o[3] = (_Float16)tanhf(acc.w);
    *(half4v*)(Xh + (size_t)row * EMB + lane * 4) = o;
}

// ---- fused hr + batchnorm (stats + apply) -> fp16; one block per feature
__global__ __launch_bounds__(256) void bn_fused(const _Float16* __restrict__ Xh,
                                                const int* __restrict__ e1,
                                                const int* __restrict__ ri,
                                                const float* __restrict__ gamma,
                                                const float* __restrict__ beta,
                                                _Float16* __restrict__ hr_h) {
    const int f = blockIdx.x, t = threadIdx.x;
    float v[4];
    float s = 0.f, sq = 0.f;
    #pragma unroll
    for (int k = 0; k < 4; ++k) {
        int b = t + k * 256;
        float h = (float)Xh[(size_t)e1[b] * EMB + f];
        float r = (float)Xh[((size_t)ri[b] + N_ENT) * EMB + f];
        v[k] = h * r;
        s += v[k]; sq += v[k] * v[k];
    }
    #pragma unroll
    for (int off = 32; off > 0; off >>= 1) {
        s  += __shfl_down(s, off);
        sq += __shfl_down(sq, off);
    }
    __shared__ float ss[4], sqs[4], mv[2];
    int w = t >> 6;
    if ((t & 63) == 0) { ss[w] = s; sqs[w] = sq; }
    __syncthreads();
    if (t == 0) {
        s  = ss[0] + ss[1] + ss[2] + ss[3];
        sq = sqs[0] + sqs[1] + sqs[2] + sqs[3];
        float m = s * (1.f / BATCH);
        mv[0] = m;
        mv[1] = sq * (1.f / BATCH) - m * m;
    }
    __syncthreads();
    float mean = mv[0];
    float inv = rsqrtf(mv[1] + BN_EPS) * gamma[f];
    float bet = beta[f];
    #pragma unroll
    for (int k = 0; k < 4; ++k) {
        int b = t + k * 256;
        hr_h[(size_t)b * EMB + f] = (_Float16)((v[k] - mean) * inv + bet);
    }
}

// ------------- out = sigmoid(hr_h @ Xh[:N_ENT]^T), fp16 MFMA LDS GEMM
__global__ __launch_bounds__(256) void score_v3(const _Float16* __restrict__ hr_h,
                                                const _Float16* __restrict__ Xh,
                                                float* __restrict__ out) {
    __shared__ char smem[64 * 132 * 4];       // 33.8 KB (>= 12 KB A+B)
    _Float16* As = (_Float16*)smem;           // [64][32]
    _Float16* Bs = As + 2048;                 // [128][32]
    float* Ep = (float*)smem;                 // [64][132]

    const int tid  = threadIdx.x;
    const int wid  = tid >> 6;
    const int lane = tid & 63;
    const int wr = wid >> 1, wc = wid & 1;
    const int row0 = blockIdx.x * 64;         // M block (16)
    const int col0 = blockIdx.y * 128;        // N block (313)
    const int fr = lane & 15;
    const int kg = lane >> 4;
    const int lrow = lane >> 2;
    const int lchk = (lane & 3) * 8;

    f32x4 acc[2][4] = {};

    for (int kb = 0; kb < 8; ++kb) {
        const int koff = kb * 32;
        #pragma unroll
        for (int c = 0; c < 3; ++c) {
            int ch = wid * 3 + c;                      // 0..11
            if (ch < 4) {
                int lr = ch * 16 + lrow;               // 0..63
                const _Float16* srcA = hr_h + (size_t)(row0 + lr) * EMB + koff + lchk;
                gl_lds16(srcA, smem + ch * 1024);
            } else {
                int br = (ch - 4) * 16 + lrow;         // 0..127
                int gc = col0 + br;
                if (gc > N_ENT - 1) gc = N_ENT - 1;
                const _Float16* srcB = Xh + (size_t)gc * EMB + koff + lchk;
                gl_lds16(srcB, smem + ch * 1024);
            }
        }
        __syncthreads();
        half8 a_[2], b_[4];
        #pragma unroll
        for (int i = 0; i < 2; ++i) {
            int r = wr * 32 + i * 16 + fr;
            a_[i] = *(const half8*)&As[r * 32 + kg * 8];
        }
        #pragma unroll
        for (int j = 0; j < 4; ++j) {
            int r = wc * 64 + j * 16 + fr;
            b_[j] = *(const half8*)&Bs[r * 32 + kg * 8];
        }
        #pragma unroll
        for (int i = 0; i < 2; ++i)
            #pragma unroll
            for (int j = 0; j < 4; ++j)
                acc[i][j] = __builtin_amdgcn_mfma_f32_16x16x32_f16(a_[i], b_[j], acc[i][j], 0, 0, 0);
        __syncthreads();
    }

    #pragma unroll
    for (int i = 0; i < 2; ++i) {
        int rl = wr * 32 + i * 16 + (lane >> 4) * 4;
        #pragma unroll
        for (int j = 0; j < 4; ++j) {
            int cl = wc * 64 + j * 16 + (lane & 15);
            #pragma unroll
            for (int r = 0; r < 4; ++r)
                Ep[(rl + r) * 132 + cl] = 1.f / (1.f + __expf(-acc[i][j][r]));
        }
    }
    __syncthreads();
    #pragma unroll
    for (int it = 0; it < 8; ++it) {
        int idx = it * 256 + tid;
        int row = idx >> 5;
        int c4 = (idx & 31) << 2;
        f32x4 v = *(const f32x4*)&Ep[row * 132 + c4];
        int gc = col0 + c4;
        if (gc < N_ENT)
            __builtin_nontemporal_store(v, (f32x4*)(out + (size_t)(row0 + row) * N_ENT + gc));
    }
}

extern "C" void kernel_launch(void* const* d_in, const int* in_sizes, int n_in,
                              void* d_out, int out_size, void* d_ws, size_t ws_size,
                              hipStream_t stream) {
    const int*   e1    = (const int*)d_in[0];
    const int*   ri    = (const int*)d_in[1];
    const float* emb   = (const float*)d_in[3];
    const float* qw    = (const float*)d_in[4];
    const int*   esrc  = (const int*)d_in[5];
    const int*   edst  = (const int*)d_in[6];
    const float* evalv = (const float*)d_in[7];
    const float* gamma = (const float*)d_in[8];
    const float* beta  = (const float*)d_in[9];
    float* out = (float*)d_out;

    const size_t NODE_F = (size_t)N_NODES * EMB;        // 10,368,000
    _Float16* support_h = (_Float16*)d_ws;              // NODE_F halfs
    _Float16* Xh        = support_h + NODE_F;           // NODE_F halfs
    int*      row_start = (int*)(Xh + NODE_F);          // N_NODES+1
    int*      cnt       = row_start + (N_NODES + 1);    // N_NODES
    int*      cursor    = cnt + N_NODES;                // N_NODES
    int*      bsum      = cursor + N_NODES;             // 41
    int2*     edge_s    = (int2*)(bsum + SCAN_NB + 1);  // N_EDGES int2 (8B-aligned)
    _Float16* hr_h      = (_Float16*)(edge_s + N_EDGES);// 262144 halfs
    _Float16* Hth       = hr_h + 262144;                // 65536 halfs

    hipMemsetAsync(cnt, 0, N_NODES * sizeof(int), stream);
    hist_k<<<(N_EDGES + 255) / 256, 256, 0, stream>>>(esrc, cnt);
    scanham<<<SCAN_NB + 64, 1024, 0, stream>>>(cnt, row_start, bsum, qw, Hth);
    scan_add<<<SCAN_NB, 1024, 0, stream>>>(row_start, cursor, bsum);
    support_place<<<633 + (N_EDGES + 255) / 256, 256, 0, stream>>>(
        emb, Hth, support_h, esrc, edst, evalv, cursor, edge_s);
    spmm_tanh<<<N_NODES / 4, 256, 0, stream>>>(row_start, edge_s, support_h, Xh);
    bn_fused<<<EMB, 256, 0, stream>>>(Xh, e1, ri, gamma, beta, hr_h);
    score_v3<<<dim3(16, 313), 256, 0, stream>>>(hr_h, Xh, out);
}